// Round 4
// baseline (7678.283 us; speedup 1.0000x reference)
//
#include <hip/hip_runtime.h>
#include <math.h>

// ---------------------------------------------------------------------------
// Refine (RE-GCN style): bf16-MFMA recurrence + decoder; f32 state.
// N_ENT=20000 N_REL=256 H=512 C=64 K=3 L=2 T=8 E=30000 B=4096
// ---------------------------------------------------------------------------

#define N_ENT 20000
#define N_REL 256
#define HD    512
#define NE    30000
#define NB    4096
#define NT    8

typedef __attribute__((ext_vector_type(8))) short          bf16x8;
typedef __attribute__((ext_vector_type(4))) float          f32x4;
typedef __attribute__((ext_vector_type(8))) unsigned short u16x8;
typedef __attribute__((ext_vector_type(4))) unsigned short u16x4;

static __device__ __forceinline__ float sigmoidf_(float x) {
  return 1.0f / (1.0f + expf(-x));
}
static __device__ __forceinline__ unsigned short f2bf(float f) {  // RNE
  unsigned u = __float_as_uint(f);
  return (unsigned short)((u + 0x7FFFu + ((u >> 16) & 1u)) >> 16);
}

// ---------------- row L2 normalize: out = x / (||x|| + 1e-8) ---------------
__global__ void rownorm_kernel(const float* __restrict__ in, float* __restrict__ out, int rows) {
  int wid = (blockIdx.x * blockDim.x + threadIdx.x) >> 6;
  int lane = threadIdx.x & 63;
  if (wid >= rows) return;
  const float4* ip = (const float4*)(in + (size_t)wid * HD);
  float4 v0 = ip[lane];
  float4 v1 = ip[lane + 64];
  float s = v0.x * v0.x + v0.y * v0.y + v0.z * v0.z + v0.w * v0.w
          + v1.x * v1.x + v1.y * v1.y + v1.z * v1.z + v1.w * v1.w;
  #pragma unroll
  for (int m = 1; m < 64; m <<= 1) s += __shfl_xor(s, m);
  float inv = 1.0f / (sqrtf(s) + 1e-8f);
  float4* op = (float4*)(out + (size_t)wid * HD);
  v0.x *= inv; v0.y *= inv; v0.z *= inv; v0.w *= inv;
  v1.x *= inv; v1.y *= inv; v1.z *= inv; v1.w *= inv;
  op[lane] = v0; op[lane + 64] = v1;
}

// ---------------- relation aggregation: agg[r] += ent[s], cnt[r]++ ----------
__global__ void agg_rel_kernel(const float* __restrict__ ent, const int* __restrict__ src,
                               const int* __restrict__ erel,
                               float* __restrict__ agg, float* __restrict__ cnt) {
  int wid = (blockIdx.x * blockDim.x + threadIdx.x) >> 6;
  int lane = threadIdx.x & 63;
  if (wid >= NE) return;
  int s = src[wid], r = erel[wid];
  const float* row = ent + (size_t)s * HD;
  float* arow = agg + (size_t)r * HD;
  #pragma unroll
  for (int j = 0; j < 8; ++j) atomicAdd(&arow[lane + 64 * j], row[lane + 64 * j]);
  if (lane == 0) atomicAdd(&cnt[r], 1.0f);
}

// ------------- entity aggregation: agg[d] += h[s] + relh[r], cnt[d]++ -------
__global__ void agg_ent_kernel(const float* __restrict__ h, const float* __restrict__ relh,
                               const int* __restrict__ src, const int* __restrict__ dst,
                               const int* __restrict__ erel,
                               float* __restrict__ agg, float* __restrict__ cnt) {
  int wid = (blockIdx.x * blockDim.x + threadIdx.x) >> 6;
  int lane = threadIdx.x & 63;
  if (wid >= NE) return;
  int s = src[wid], d = dst[wid], r = erel[wid];
  const float* hr = h + (size_t)s * HD;
  const float* rr = relh + (size_t)r * HD;
  float* arow = agg + (size_t)d * HD;
  #pragma unroll
  for (int j = 0; j < 8; ++j) {
    int i = lane + 64 * j;
    atomicAdd(&arow[i], hr[i] + rr[i]);
  }
  if (lane == 0) atomicAdd(&cnt[d], 1.0f);
}

// ---------------- GRU elementwise (biases folded in here) ------------------
__global__ void gru_kernel(const float* __restrict__ gi, const float* __restrict__ gh,
                           const float* __restrict__ bih, const float* __restrict__ bhh,
                           float* __restrict__ relh) {
  int i = blockIdx.x * blockDim.x + threadIdx.x;
  if (i >= N_REL * HD) return;
  int row = i >> 9, col = i & 511;
  const float* gir = gi + (size_t)row * 1536;
  const float* ghr = gh + (size_t)row * 1536;
  float ir = gir[col] + bih[col];
  float iz = gir[col + 512] + bih[col + 512];
  float inn = gir[col + 1024] + bih[col + 1024];
  float hr = ghr[col] + bhh[col];
  float hz = ghr[col + 512] + bhh[col + 512];
  float hn = ghr[col + 1024] + bhh[col + 1024];
  float r = sigmoidf_(ir + hr);
  float z = sigmoidf_(iz + hz);
  float n = tanhf(inn + r * hn);
  relh[i] = (1.0f - z) * n + z * relh[i];
}

// ---------------- gather rows (f32) ----------------------------------------
__global__ void gather_kernel(const float* __restrict__ table, const int* __restrict__ idx,
                              float* __restrict__ out, int rows) {
  int i = blockIdx.x * blockDim.x + threadIdx.x;
  if (i >= rows * (HD / 4)) return;
  int row = i >> 7, q = i & 127;
  ((float4*)out)[i] = ((const float4*)(table + (size_t)idx[row] * HD))[q];
}

// ---------------- flat f32 -> bf16 convert (n multiple of 8) ---------------
__global__ void f2b_kernel(const float* __restrict__ in, unsigned short* __restrict__ out, int n) {
  int i = blockIdx.x * blockDim.x + threadIdx.x;
  if (i * 8 >= n) return;
  float4 a = *(const float4*)&in[i * 8];
  float4 b = *(const float4*)&in[i * 8 + 4];
  u16x8 pk = {f2bf(a.x), f2bf(a.y), f2bf(a.z), f2bf(a.w),
              f2bf(b.x), f2bf(b.y), f2bf(b.z), f2bf(b.w)};
  *(u16x8*)&out[i * 8] = pk;
}

// ---------------------------------------------------------------------------
// pack_nn: B (KxN f32 row-major) -> bf16 LDS-image layout:
// step s (32 k): idx = (s*N + n)*32 + ((g ^ ((n>>2)&3))<<3) + j  holds
// B[s*32 + g*8 + j][n].  One thread per u16x8.
// ---------------------------------------------------------------------------
__global__ void pack_nn_kernel(const float* __restrict__ B, unsigned short* __restrict__ out,
                               int K, int N) {
  int id = blockIdx.x * 256 + threadIdx.x;
  if (id >= (K >> 3) * N) return;
  int s = id / (N * 4);
  int rem = id - s * (N * 4);
  int n = rem >> 2, g = rem & 3;
  const float* src = B + (size_t)(s * 32 + g * 8) * N + n;
  u16x8 pk;
  #pragma unroll
  for (int j = 0; j < 8; ++j) pk[j] = f2bf(src[(size_t)j * N]);
  *(u16x8*)&out[((size_t)s * N + n) * 32 + ((g ^ ((n >> 2) & 3)) << 3)] = pk;
}

// ---------------------------------------------------------------------------
// bf16 NN GEMM with f32 A (converted during staging) and pre-packed B image.
// A = [A0 (M x K0) | A1 (M x K1)] concatenated along K (K0 % 64 == 0).
// SCALEA0: scale A0 rows by 1/max(cnt[row],1) during staging (seg-mean fold).
// ACT: 0 plain store, 1 relu, 3 gate: u=sigmoid(acc+bias[n]); C=u*D+(1-u)*C.
// ---------------------------------------------------------------------------
template <int ACT, int SCALEA0>
__global__ __launch_bounds__(256, 2)
void gemm_nn_bf16(const float* __restrict__ A0, const float* __restrict__ A1,
                  int K0, int K1, const float* __restrict__ cntA,
                  const unsigned short* __restrict__ Bp,
                  const float* __restrict__ bias, const float* __restrict__ D,
                  float* __restrict__ C, int M, int N) {
  __shared__ unsigned short As[128 * 64];     // 16KB: row*64 + (chunk ^ (row&7))*8
  __shared__ unsigned short Bs[2 * 128 * 32]; // 16KB: (step*128 + nl)*32 + slot*8
  const int tid = threadIdx.x;
  const int lane = tid & 63;
  const int w = tid >> 6;
  const int wm = w >> 1, wn = w & 1;
  const int m0 = blockIdx.x * 128, n0 = blockIdx.y * 128;
  const int lr = lane & 15, lg = lane >> 4;
  const int K = K0 + K1;
  const int arow = tid >> 1;
  const int akh = (tid & 1) * 32;

  float s0 = 1.0f;
  if (SCALEA0 && m0 + arow < M) s0 = 1.0f / fmaxf(cntA[m0 + arow], 1.0f);

  f32x4 acc[4][4];
  #pragma unroll
  for (int i = 0; i < 4; ++i)
    #pragma unroll
    for (int j = 0; j < 4; ++j) acc[i][j] = (f32x4){0.f, 0.f, 0.f, 0.f};

  for (int k0 = 0; k0 < K; k0 += 64) {
    __syncthreads();
    // ---- A stage: f32 -> bf16 into swizzled LDS ----
    {
      int mrow = m0 + arow;
      int kk = k0 + akh;                       // uniform side of K0 (K0%64==0)
      const float* base; int stride, kloc;
      float sc;
      if (kk < K0) { base = A0; stride = K0; kloc = kk; sc = SCALEA0 ? s0 : 1.0f; }
      else         { base = A1; stride = K1; kloc = kk - K0; sc = 1.0f; }
      u16x8 pk[4];
      if (mrow < M) {
        const float* p = base + (size_t)mrow * stride + kloc;
        #pragma unroll
        for (int q = 0; q < 4; ++q) {
          float4 x = *(const float4*)(p + q * 8);
          float4 y = *(const float4*)(p + q * 8 + 4);
          pk[q] = (u16x8){f2bf(x.x * sc), f2bf(x.y * sc), f2bf(x.z * sc), f2bf(x.w * sc),
                          f2bf(y.x * sc), f2bf(y.y * sc), f2bf(y.z * sc), f2bf(y.w * sc)};
        }
      } else {
        #pragma unroll
        for (int q = 0; q < 4; ++q) pk[q] = (u16x8){0, 0, 0, 0, 0, 0, 0, 0};
      }
      #pragma unroll
      for (int q = 0; q < 4; ++q) {
        int chunk = (akh >> 3) + q;
        *(u16x8*)&As[arow * 64 + ((chunk ^ (arow & 7)) << 3)] = pk[q];
      }
    }
    // ---- B stage: identity copy of 2 pre-swizzled 32-k steps ----
    {
      int s = k0 >> 5;
      #pragma unroll
      for (int sl = 0; sl < 2; ++sl) {
        const unsigned short* src = Bp + ((size_t)(s + sl) * N + n0) * 32;
        #pragma unroll
        for (int q = 0; q < 2; ++q) {
          int off = (q * 256 + tid) * 8;
          *(u16x8*)&Bs[sl * 4096 + off] = *(const u16x8*)&src[off];
        }
      }
    }
    __syncthreads();
    // ---- MFMA ----
    #pragma unroll
    for (int u = 0; u < 2; ++u) {
      bf16x8 a[4], b[4];
      #pragma unroll
      for (int i = 0; i < 4; ++i) {
        int r = wm * 64 + i * 16 + lr;
        a[i] = *(const bf16x8*)&As[r * 64 + (((u * 4 + lg) ^ (r & 7)) << 3)];
        int nl = wn * 64 + i * 16 + lr;
        b[i] = *(const bf16x8*)&Bs[u * 4096 + nl * 32 + ((lg ^ ((nl >> 2) & 3)) << 3)];
      }
      #pragma unroll
      for (int i = 0; i < 4; ++i)
        #pragma unroll
        for (int j = 0; j < 4; ++j)
          acc[i][j] = __builtin_amdgcn_mfma_f32_16x16x32_bf16(a[i], b[j], acc[i][j], 0, 0, 0);
    }
  }

  // ---- epilogue ----
  #pragma unroll
  for (int i = 0; i < 4; ++i) {
    int m = m0 + wm * 64 + i * 16 + lg * 4;
    #pragma unroll
    for (int j = 0; j < 4; ++j) {
      int n = n0 + wn * 64 + j * 16 + lr;
      #pragma unroll
      for (int q = 0; q < 4; ++q) {
        int mr = m + q;
        if (mr >= M) continue;
        size_t o = (size_t)mr * N + n;
        float v = acc[i][j][q];
        if (ACT == 0) {
          C[o] = v;
        } else if (ACT == 1) {
          C[o] = fmaxf(v, 0.0f);
        } else {  // gate
          float u_ = sigmoidf_(v + bias[n]);
          C[o] = u_ * D[o] + (1.0f - u_) * C[o];
        }
      }
    }
  }
}

// ---------------------------------------------------------------------------
// pack_fw: fw (32768x512 f32) -> bf16 image (same layout as pack_nn, N=512)
// ---------------------------------------------------------------------------
__global__ __launch_bounds__(256)
void pack_fw_kernel(const float* __restrict__ f0, const float* __restrict__ f1,
                    const float* __restrict__ f2, const float* __restrict__ f3,
                    unsigned short* __restrict__ o0, unsigned short* __restrict__ o1,
                    unsigned short* __restrict__ o2, unsigned short* __restrict__ o3) {
  __shared__ float L[32][512];
  const float* fw; unsigned short* op;
  switch (blockIdx.y) {
    case 0: fw = f0; op = o0; break;
    case 1: fw = f1; op = o1; break;
    case 2: fw = f2; op = o2; break;
    default: fw = f3; op = o3; break;
  }
  int s = blockIdx.x, tid = threadIdx.x;
  #pragma unroll
  for (int i = 0; i < 16; ++i) {
    int idx = tid + 256 * i;
    int r = idx >> 7, cq = (idx & 127) << 2;
    *(float4*)&L[r][cq] = *(const float4*)&fw[(size_t)(s * 32 + r) * 512 + cq];
  }
  __syncthreads();
  #pragma unroll
  for (int ii = 0; ii < 8; ++ii) {
    int slot = tid + 256 * ii;
    int n = slot >> 2, g = slot & 3;
    u16x8 pk;
    #pragma unroll
    for (int j = 0; j < 8; ++j) pk[j] = f2bf(L[g * 8 + j][n]);
    size_t off = (size_t)s * 16384 + n * 32 + ((g ^ ((n >> 2) & 3)) << 3);
    *(u16x8*)&op[off] = pk;
  }
}

// ---------------------------------------------------------------------------
// Fused conv1d('SAME',K=3)+relu -> bf16 MFMA GEMM against packed fw.
// BM=128, BN=128, BK=32, KSPLIT=8 (8 channels/block, 128 K-steps).
// Grid (32 m, 4 n, path*8+ks) natural order; 2x2 waves, 64x64 wave tile.
// B double-buffered in LDS via register prefetch (issue-early/write-late).
// ---------------------------------------------------------------------------
template <int CIN>
__global__ __launch_bounds__(256, 3)
void convfc_mfma(const float* __restrict__ X0e, const float* __restrict__ X1e,
                 const float* __restrict__ X2e, const float* __restrict__ cwE,
                 const float* __restrict__ cbE, const unsigned short* __restrict__ fwpE,
                 const float* __restrict__ X0r, const float* __restrict__ X1r,
                 const float* __restrict__ X2r, const float* __restrict__ cwR,
                 const float* __restrict__ cbR, const unsigned short* __restrict__ fwpR,
                 float* __restrict__ partE, float* __restrict__ partR) {
  __shared__ unsigned short As[128 * 32];      // 8KB : m*32 + (g ^ ((m>>2)&3))*8
  __shared__ unsigned short Bs[2][128 * 32];   // 2x8KB double buffer

  const int tid = threadIdx.x;
  const int lane = tid & 63;
  const int w = tid >> 6;
  const int wm = w >> 1, wn = w & 1;
  const int m0 = blockIdx.x * 128;
  const int n0 = blockIdx.y * 128;
  const int path = blockIdx.z >> 3;
  const int ks = blockIdx.z & 7;

  const float* X[CIN];
  const float* cw; const float* cb; const unsigned short* fwp; float* part;
  if (path == 0) {
    X[0] = X0e; X[1] = X1e; if constexpr (CIN == 3) X[2] = X2e;
    cw = cwE; cb = cbE; fwp = fwpE; part = partE;
  } else {
    X[0] = X0r; X[1] = X1r; if constexpr (CIN == 3) X[2] = X2r;
    cw = cwR; cb = cbR; fwp = fwpR; part = partR;
  }
  part += (size_t)ks * (NB * HD);

  f32x4 acc[4][4];
  #pragma unroll
  for (int i = 0; i < 4; ++i)
    #pragma unroll
    for (int j = 0; j < 4; ++j) acc[i][j] = (f32x4){0.f, 0.f, 0.f, 0.f};

  const int lr = lane & 15, lg = lane >> 4;
  float wv[CIN][3];
  float cbv = 0.f;

  // B slice (8KB) source for K-step sl: image step s = (ks*8 + sl>>4)*16 + (sl&15)
  auto bsrc = [&](int sl) {
    int s = (ks * 8 + (sl >> 4)) * 16 + (sl & 15);
    return fwp + (size_t)s * 16384 + (size_t)n0 * 32;
  };

  // ---- prologue: B(0) straight into Bs[0] ----
  {
    const unsigned short* src = bsrc(0);
    *(u16x8*)&Bs[0][tid * 8] = *(const u16x8*)&src[tid * 8];
    *(u16x8*)&Bs[0][2048 + tid * 8] = *(const u16x8*)&src[2048 + tid * 8];
  }

  for (int sl = 0; sl < 128; ++sl) {
    const int cur = sl & 1;
    const int c = ks * 8 + (sl >> 4);
    const int hb = (sl & 15) * 32;
    if ((sl & 15) == 0) {
      #pragma unroll
      for (int ci = 0; ci < CIN; ++ci)
        #pragma unroll
        for (int t = 0; t < 3; ++t) wv[ci][t] = cw[(c * CIN + ci) * 3 + t];
      cbv = cb[c];
    }

    // ---- prefetch B(sl+1) into registers (latency hides under conv+MFMA) ----
    u16x8 br0, br1;
    if (sl < 127) {
      const unsigned short* src = bsrc(sl + 1);
      br0 = *(const u16x8*)&src[tid * 8];
      br1 = *(const u16x8*)&src[2048 + tid * 8];
    }

    // ---- conv A on the fly: 2 chunks of (row, 8 h-values) ----
    #pragma unroll
    for (int cc = 0; cc < 2; ++cc) {
      int cid = tid + cc * 256;
      int m = cid >> 2, g = cid & 3;
      int h = hb + g * 8;
      float v[8];
      #pragma unroll
      for (int e = 0; e < 8; ++e) v[e] = cbv;
      #pragma unroll
      for (int ci = 0; ci < CIN; ++ci) {
        const float* xr = X[ci] + (size_t)(m0 + m) * HD + h;
        float4 a4 = *(const float4*)xr;
        float4 b4 = *(const float4*)(xr + 4);
        float xm[8] = {a4.x, a4.y, a4.z, a4.w, b4.x, b4.y, b4.z, b4.w};
        float xl = (h > 0) ? xr[-1] : 0.f;
        float xrr = (h + 8 < HD) ? xr[8] : 0.f;
        float w0 = wv[ci][0], w1 = wv[ci][1], w2 = wv[ci][2];
        #pragma unroll
        for (int e = 0; e < 8; ++e) {
          float lft = e ? xm[e - 1] : xl;
          float rgt = (e < 7) ? xm[e + 1] : xrr;
          v[e] = fmaf(lft, w0, fmaf(xm[e], w1, fmaf(rgt, w2, v[e])));
        }
      }
      u16x8 pk;
      #pragma unroll
      for (int e = 0; e < 8; ++e) pk[e] = f2bf(fmaxf(v[e], 0.f));
      int slot = g ^ ((m >> 2) & 3);
      *(u16x8*)&As[m * 32 + slot * 8] = pk;
    }
    __syncthreads();   // As visible; B(sl) LDS writes visible; prefetch regs landed

    // ---- MFMA on Bs[cur] ----
    bf16x8 a[4];
    #pragma unroll
    for (int i = 0; i < 4; ++i) {
      int m = wm * 64 + i * 16 + lr;
      a[i] = *(const bf16x8*)&As[m * 32 + (lg ^ ((m >> 2) & 3)) * 8];
    }
    #pragma unroll
    for (int j = 0; j < 4; ++j) {
      int nl = wn * 64 + j * 16 + lr;
      bf16x8 b = *(const bf16x8*)&Bs[cur][nl * 32 + (lg ^ ((nl >> 2) & 3)) * 8];
      #pragma unroll
      for (int i = 0; i < 4; ++i)
        acc[i][j] = __builtin_amdgcn_mfma_f32_16x16x32_bf16(a[i], b, acc[i][j], 0, 0, 0);
    }

    // ---- write-late: land prefetched B(sl+1) into the other buffer ----
    if (sl < 127) {
      *(u16x8*)&Bs[cur ^ 1][tid * 8] = br0;
      *(u16x8*)&Bs[cur ^ 1][2048 + tid * 8] = br1;
    }
    __syncthreads();   // readers of As/Bs[cur] done before next iter overwrites
  }

  // ---- epilogue: write f32 partial ----
  #pragma unroll
  for (int i = 0; i < 4; ++i) {
    int mrow = m0 + wm * 64 + i * 16 + lg * 4;
    #pragma unroll
    for (int j = 0; j < 4; ++j) {
      int ncol = n0 + wn * 64 + j * 16 + lr;
      #pragma unroll
      for (int q = 0; q < 4; ++q)
        part[(size_t)(mrow + q) * HD + ncol] = acc[i][j][q];
    }
  }
}

// ---------------------------------------------------------------------------
// reduce 8 split-K partials + bias + relu -> f32 out AND bf16 out
// ---------------------------------------------------------------------------
__global__ void reduce8_kernel(const float* __restrict__ pE, const float* __restrict__ pR,
                               const float* __restrict__ bE, const float* __restrict__ bR,
                               float* __restrict__ oE, float* __restrict__ oR,
                               unsigned short* __restrict__ obE, unsigned short* __restrict__ obR) {
  int p = blockIdx.y;
  const float* part = p ? pR : pE;
  const float* bias = p ? bR : bE;
  float* o = p ? oR : oE;
  unsigned short* ob = p ? obR : obE;
  int i = blockIdx.x * 256 + threadIdx.x;
  int col = (i << 2) & 511;
  float4 s = *(const float4*)&part[(size_t)i * 4];
  #pragma unroll
  for (int ks = 1; ks < 8; ++ks) {
    float4 t = *(const float4*)&part[(size_t)ks * (NB * HD) + i * 4];
    s.x += t.x; s.y += t.y; s.z += t.z; s.w += t.w;
  }
  float4 b4 = *(const float4*)&bias[col];
  s.x = fmaxf(s.x + b4.x, 0.f); s.y = fmaxf(s.y + b4.y, 0.f);
  s.z = fmaxf(s.z + b4.z, 0.f); s.w = fmaxf(s.w + b4.w, 0.f);
  *(float4*)&o[(size_t)i * 4] = s;
  u16x4 pk = {f2bf(s.x), f2bf(s.y), f2bf(s.z), f2bf(s.w)};
  *(u16x4*)&ob[(size_t)i * 4] = pk;
}

// ---------------------------------------------------------------------------
// bf16 NT GEMM: C(MxN, f32) = A(MxK) @ B(NxK)^T, both bf16 row-major.
// ---------------------------------------------------------------------------
__global__ __launch_bounds__(256, 3)
void gemm_nt_bf16(const unsigned short* __restrict__ A, const unsigned short* __restrict__ B,
                  float* __restrict__ C, int M, int N, int K) {
  __shared__ unsigned short As[128 * 64];
  __shared__ unsigned short Bs[128 * 64];
  const int tid = threadIdx.x;
  const int lane = tid & 63;
  const int w = tid >> 6;
  const int wm = w >> 1, wn = w & 1;
  const int m0 = blockIdx.x * 128, n0 = blockIdx.y * 128;
  const int lr = lane & 15, lg = lane >> 4;

  f32x4 acc[4][4];
  #pragma unroll
  for (int i = 0; i < 4; ++i)
    #pragma unroll
    for (int j = 0; j < 4; ++j) acc[i][j] = (f32x4){0.f, 0.f, 0.f, 0.f};

  for (int k0 = 0; k0 < K; k0 += 64) {
    __syncthreads();
    {
      int row = tid >> 1, half = tid & 1;
      const unsigned short* asrc = A + (size_t)(m0 + row) * K + k0 + half * 32;
      #pragma unroll
      for (int q = 0; q < 4; ++q) {
        int chunk = half * 4 + q;
        *(u16x8*)&As[row * 64 + (chunk ^ (row & 7)) * 8] = *(const u16x8*)&asrc[q * 8];
      }
      int nrow = n0 + row;
      const unsigned short* bsrc = B + (size_t)nrow * K + k0 + half * 32;
      u16x8 z = {0, 0, 0, 0, 0, 0, 0, 0};
      #pragma unroll
      for (int q = 0; q < 4; ++q) {
        int chunk = half * 4 + q;
        u16x8 v = (nrow < N) ? *(const u16x8*)&bsrc[q * 8] : z;
        *(u16x8*)&Bs[row * 64 + (chunk ^ (row & 7)) * 8] = v;
      }
    }
    __syncthreads();
    #pragma unroll
    for (int u = 0; u < 2; ++u) {
      bf16x8 a[4], b[4];
      #pragma unroll
      for (int i = 0; i < 4; ++i) {
        int r = wm * 64 + i * 16 + lr;
        a[i] = *(const bf16x8*)&As[r * 64 + (((u * 4 + lg) ^ (r & 7))) * 8];
        int n = wn * 64 + i * 16 + lr;
        b[i] = *(const bf16x8*)&Bs[n * 64 + (((u * 4 + lg) ^ (n & 7))) * 8];
      }
      #pragma unroll
      for (int i = 0; i < 4; ++i)
        #pragma unroll
        for (int j = 0; j < 4; ++j)
          acc[i][j] = __builtin_amdgcn_mfma_f32_16x16x32_bf16(a[i], b[j], acc[i][j], 0, 0, 0);
    }
  }

  #pragma unroll
  for (int i = 0; i < 4; ++i) {
    int m = m0 + wm * 64 + i * 16 + lg * 4;
    #pragma unroll
    for (int j = 0; j < 4; ++j) {
      int n = n0 + wn * 64 + j * 16 + lr;
      if (n < N) {
        #pragma unroll
        for (int q = 0; q < 4; ++q)
          C[(size_t)(m + q) * N + n] = acc[i][j][q];
      }
    }
  }
}

// ---------------------------------------------------------------------------
extern "C" void kernel_launch(void* const* d_in, const int* in_sizes, int n_in,
                              void* d_out, int out_size, void* d_ws, size_t ws_size,
                              hipStream_t stream) {
  const float* ent_embeds = (const float*)d_in[0];
  const float* rel_embeds = (const float*)d_in[1];
  const float* W_msg  = (const float*)d_in[2];
  const float* W_self = (const float*)d_in[3];
  const float* gru_Wih = (const float*)d_in[4];
  const float* gru_Whh = (const float*)d_in[5];
  const float* gru_bih = (const float*)d_in[6];
  const float* gru_bhh = (const float*)d_in[7];
  const float* gate_W = (const float*)d_in[8];
  const float* gate_b = (const float*)d_in[9];
  const float* e_conv1 = (const float*)d_in[10]; const float* e_cb1 = (const float*)d_in[11];
  const float* e_fc1   = (const float*)d_in[12]; const float* e_fb1 = (const float*)d_in[13];
  const float* e_conv2 = (const float*)d_in[14]; const float* e_cb2 = (const float*)d_in[15];
  const float* e_fc2   = (const float*)d_in[16]; const float* e_fb2 = (const float*)d_in[17];
  const float* r_conv1 = (const float*)d_in[18]; const float* r_cb1 = (const float*)d_in[19];
  const float* r_fc1   = (const float*)d_in[20]; const float* r_fb1 = (const float*)d_in[21];
  const float* r_conv2 = (const float*)d_in[22]; const float* r_cb2 = (const float*)d_in[23];
  const float* r_fc2   = (const float*)d_in[24]; const float* r_fb2 = (const float*)d_in[25];
  const int* src  = (const int*)d_in[26];
  const int* dst  = (const int*)d_in[27];
  const int* erel = (const int*)d_in[28];
  const int* subj = (const int*)d_in[29];
  const int* rel  = (const int*)d_in[30];
  const int* obj  = (const int*)d_in[31];
  float* out = (float*)d_out;

  // -------- workspace layout --------
  float* w = (float*)d_ws;
  float* ent   = w; w += (size_t)N_ENT * HD;
  float* relh  = w; w += (size_t)N_REL * HD;
  float* aggR  = w; w += (size_t)N_REL * HD;
  float* cntR  = w; w += N_REL;
  float* gi    = w; w += (size_t)N_REL * 1536;
  float* gh    = w; w += (size_t)N_REL * 1536;
  float* aggE  = w; w += (size_t)N_ENT * HD;     // } aggE..h1b reused post-loop as
  float* cntE  = w; w += N_ENT;                  // } packed-fw storage (33.6M f32
  float* tmp   = w; w += (size_t)N_ENT * HD;     // } needed; region has 41M)
  float* h0b   = w; w += (size_t)N_ENT * HD;
  float* h1b   = w; w += (size_t)N_ENT * HD;
  float* se    = w; w += (size_t)NB * HD;
  float* re_   = w; w += (size_t)NB * HD;
  float* oe    = w; w += (size_t)NB * HD;
  float* o1    = w; w += (size_t)NB * HD;
  float* q1    = w; w += (size_t)NB * HD;
  float* o2    = w; w += (size_t)NB * HD;
  float* q2    = w; w += (size_t)NB * HD;
  unsigned short* ent_bf = (unsigned short*)w; w += (size_t)N_ENT * HD / 2;
  unsigned short* relh_bf = (unsigned short*)w; w += (size_t)N_REL * HD / 2;
  unsigned short* o1b = (unsigned short*)w; w += (size_t)NB * HD / 2;
  unsigned short* q1b = (unsigned short*)w; w += (size_t)NB * HD / 2;
  unsigned short* o2b = (unsigned short*)w; w += (size_t)NB * HD / 2;
  unsigned short* q2b = (unsigned short*)w; w += (size_t)NB * HD / 2;
  // recurrence weight packs (bf16), live across the whole call
  unsigned short* wp_ih = (unsigned short*)w;    // 1024x1536
  unsigned short* wp_hh = wp_ih + (size_t)1024 * 1536;   // 512x1536
  unsigned short* wp_l0 = wp_hh + (size_t)512 * 1536;    // 1024x512
  unsigned short* wp_l1 = wp_l0 + (size_t)1024 * 512;    // 1024x512
  unsigned short* wp_g  = wp_l1 + (size_t)1024 * 512;    // 512x512
  // fw packs alias the recurrence temporaries (used only post-loop)
  unsigned short* fwp0 = (unsigned short*)aggE;
  unsigned short* fwp1 = fwp0 + (size_t)16777216;
  unsigned short* fwp2 = fwp1 + (size_t)16777216;
  unsigned short* fwp3 = fwp2 + (size_t)16777216;
  (void)tmp; (void)h0b;
  // split-K partials live in d_out (written+consumed before logit GEMMs)
  float* pE = out;                               // 8 * NB*HD
  float* pR = out + (size_t)8 * NB * HD;         // 8 * NB*HD  (total 33.6M < 166M)

  const dim3 g_gru(2, 12);     // 256 x 1536
  const dim3 g_ent(157, 4);    // 20000 x 512

  // -------- weight packing (once) --------
  {
    int t;
    t = (1024 * 1536) / 8; pack_nn_kernel<<<(t + 255) / 256, 256, 0, stream>>>(gru_Wih, wp_ih, 1024, 1536);
    t = (512 * 1536) / 8;  pack_nn_kernel<<<(t + 255) / 256, 256, 0, stream>>>(gru_Whh, wp_hh, 512, 1536);
    t = (512 * 512) / 8;
    pack_nn_kernel<<<(t + 255) / 256, 256, 0, stream>>>(W_msg, wp_l0, 512, 512);
    pack_nn_kernel<<<(t + 255) / 256, 256, 0, stream>>>(W_self, wp_l0 + (size_t)512 * 512, 512, 512);
    pack_nn_kernel<<<(t + 255) / 256, 256, 0, stream>>>(W_msg + (size_t)512 * 512, wp_l1, 512, 512);
    pack_nn_kernel<<<(t + 255) / 256, 256, 0, stream>>>(W_self + (size_t)512 * 512, wp_l1 + (size_t)512 * 512, 512, 512);
    pack_nn_kernel<<<(t + 255) / 256, 256, 0, stream>>>(gate_W, wp_g, 512, 512);
  }

  // -------- init --------
  rownorm_kernel<<<N_ENT / 4, 256, 0, stream>>>(ent_embeds, ent, N_ENT);
  hipMemcpyAsync(relh, rel_embeds, (size_t)N_REL * HD * 4, hipMemcpyDeviceToDevice, stream);

  // -------- timestep loop --------
  for (int t = 0; t < NT; ++t) {
    const int* st = src + t * NE;
    const int* dt = dst + t * NE;
    const int* rt = erel + t * NE;

    hipMemsetAsync(aggR, 0, ((size_t)N_REL * HD + N_REL) * 4, stream);
    agg_rel_kernel<<<NE / 4, 256, 0, stream>>>(ent, st, rt, aggR, cntR);
    // gi = [mean-agg | rel_embeds] @ Wih ; gh = relh @ Whh (mean folded via SCALEA0)
    gemm_nn_bf16<0, 1><<<g_gru, 256, 0, stream>>>(aggR, rel_embeds, 512, 512, cntR, wp_ih,
                                                  nullptr, nullptr, gi, N_REL, 1536);
    gemm_nn_bf16<0, 0><<<g_gru, 256, 0, stream>>>(relh, relh, 512, 0, nullptr, wp_hh,
                                                  nullptr, nullptr, gh, N_REL, 1536);
    gru_kernel<<<(N_REL * HD) / 256, 256, 0, stream>>>(gi, gh, gru_bih, gru_bhh, relh);

    // entity evolution: per layer ONE fused GEMM h = relu([mean-agg|h] @ [Wmsg;Wself])
    const float* hcur = ent;
    float* bufs[2] = {h0b, h1b};
    const unsigned short* wls[2] = {wp_l0, wp_l1};
    for (int l = 0; l < 2; ++l) {
      hipMemsetAsync(aggE, 0, ((size_t)N_ENT * HD + N_ENT) * 4, stream);
      agg_ent_kernel<<<NE / 4, 256, 0, stream>>>(hcur, relh, st, dt, rt, aggE, cntE);
      gemm_nn_bf16<1, 1><<<g_ent, 256, 0, stream>>>(aggE, hcur, 512, 512, cntE, wls[l],
                                                    nullptr, nullptr, bufs[l], N_ENT, 512);
      hcur = bufs[l];
    }
    rownorm_kernel<<<N_ENT / 4, 256, 0, stream>>>(h1b, h1b, N_ENT);
    gemm_nn_bf16<3, 0><<<g_ent, 256, 0, stream>>>(h1b, h1b, 512, 0, nullptr, wp_g,
                                                  gate_b, h1b, ent, N_ENT, 512);
  }

  // -------- decoder prep --------
  pack_fw_kernel<<<dim3(1024, 4), 256, 0, stream>>>(e_fc1, r_fc1, e_fc2, r_fc2,
                                                    fwp0, fwp1, fwp2, fwp3);
  f2b_kernel<<<(N_ENT * HD / 8) / 256, 256, 0, stream>>>(ent, ent_bf, N_ENT * HD);
  f2b_kernel<<<(N_REL * HD / 8) / 256, 256, 0, stream>>>(relh, relh_bf, N_REL * HD);
  gather_kernel<<<(NB * HD / 4) / 256, 256, 0, stream>>>(ent, subj, se, NB);
  gather_kernel<<<(NB * HD / 4) / 256, 256, 0, stream>>>(relh, rel, re_, NB);
  gather_kernel<<<(NB * HD / 4) / 256, 256, 0, stream>>>(ent, obj, oe, NB);

  // -------- decoder stage 1 --------
  convfc_mfma<2><<<dim3(32, 4, 16), 256, 0, stream>>>(
      se, re_, nullptr, e_conv1, e_cb1, fwp0,
      se, oe, nullptr, r_conv1, r_cb1, fwp1, pE, pR);
  reduce8_kernel<<<dim3(NB * HD / 4 / 256, 2), 256, 0, stream>>>(
      pE, pR, e_fb1, r_fb1, o1, q1, o1b, q1b);

  // -------- decoder stage 2 --------
  convfc_mfma<3><<<dim3(32, 4, 16), 256, 0, stream>>>(
      o1, se, re_, e_conv2, e_cb2, fwp2,
      q1, se, oe, r_conv2, r_cb2, fwp3, pE, pR);
  reduce8_kernel<<<dim3(NB * HD / 4 / 256, 2), 256, 0, stream>>>(
      pE, pR, e_fb2, r_fb2, o2, q2, o2b, q2b);

  // -------- logits (bf16 MFMA) --------
  size_t off0 = 0;
  size_t off1 = (size_t)NB * N_ENT;
  size_t off2 = off1 + (size_t)NB * N_REL;
  size_t off3 = off2 + (size_t)NB * N_ENT;
  gemm_nt_bf16<<<dim3(32, 157), 256, 0, stream>>>(o1b, ent_bf, out + off0, NB, N_ENT, HD);
  gemm_nt_bf16<<<dim3(32, 2), 256, 0, stream>>>(q1b, relh_bf, out + off1, NB, N_REL, HD);
  gemm_nt_bf16<<<dim3(32, 157), 256, 0, stream>>>(o2b, ent_bf, out + off2, NB, N_ENT, HD);
  gemm_nt_bf16<<<dim3(32, 2), 256, 0, stream>>>(q2b, relh_bf, out + off3, NB, N_REL, HD);
}

// Round 5
// 5490.178 us; speedup vs baseline: 1.3985x; 1.3985x over previous
//
#include <hip/hip_runtime.h>
#include <math.h>

// ---------------------------------------------------------------------------
// Refine (RE-GCN style): bf16-MFMA recurrence + decoder; f32 state.
// Decoder conv+FC decoupled: convgen writes A_conv (bf16, in d_out scratch),
// gemm_fc is a single-barrier double-buffered MFMA GEMM.
// N_ENT=20000 N_REL=256 H=512 C=64 K=3 L=2 T=8 E=30000 B=4096
// ---------------------------------------------------------------------------

#define N_ENT 20000
#define N_REL 256
#define HD    512
#define NE    30000
#define NB    4096
#define NT    8

typedef __attribute__((ext_vector_type(8))) short          bf16x8;
typedef __attribute__((ext_vector_type(4))) float          f32x4;
typedef __attribute__((ext_vector_type(8))) unsigned short u16x8;
typedef __attribute__((ext_vector_type(4))) unsigned short u16x4;

static __device__ __forceinline__ float sigmoidf_(float x) {
  return 1.0f / (1.0f + expf(-x));
}
static __device__ __forceinline__ unsigned short f2bf(float f) {  // RNE
  unsigned u = __float_as_uint(f);
  return (unsigned short)((u + 0x7FFFu + ((u >> 16) & 1u)) >> 16);
}

// ---------------- row L2 normalize: out = x / (||x|| + 1e-8) ---------------
__global__ void rownorm_kernel(const float* __restrict__ in, float* __restrict__ out, int rows) {
  int wid = (blockIdx.x * blockDim.x + threadIdx.x) >> 6;
  int lane = threadIdx.x & 63;
  if (wid >= rows) return;
  const float4* ip = (const float4*)(in + (size_t)wid * HD);
  float4 v0 = ip[lane];
  float4 v1 = ip[lane + 64];
  float s = v0.x * v0.x + v0.y * v0.y + v0.z * v0.z + v0.w * v0.w
          + v1.x * v1.x + v1.y * v1.y + v1.z * v1.z + v1.w * v1.w;
  #pragma unroll
  for (int m = 1; m < 64; m <<= 1) s += __shfl_xor(s, m);
  float inv = 1.0f / (sqrtf(s) + 1e-8f);
  float4* op = (float4*)(out + (size_t)wid * HD);
  v0.x *= inv; v0.y *= inv; v0.z *= inv; v0.w *= inv;
  v1.x *= inv; v1.y *= inv; v1.z *= inv; v1.w *= inv;
  op[lane] = v0; op[lane + 64] = v1;
}

// ---------------- relation aggregation: agg[r] += ent[s], cnt[r]++ ----------
__global__ void agg_rel_kernel(const float* __restrict__ ent, const int* __restrict__ src,
                               const int* __restrict__ erel,
                               float* __restrict__ agg, float* __restrict__ cnt) {
  int wid = (blockIdx.x * blockDim.x + threadIdx.x) >> 6;
  int lane = threadIdx.x & 63;
  if (wid >= NE) return;
  int s = src[wid], r = erel[wid];
  const float* row = ent + (size_t)s * HD;
  float* arow = agg + (size_t)r * HD;
  #pragma unroll
  for (int j = 0; j < 8; ++j) atomicAdd(&arow[lane + 64 * j], row[lane + 64 * j]);
  if (lane == 0) atomicAdd(&cnt[r], 1.0f);
}

// ------------- entity aggregation: agg[d] += h[s] + relh[r], cnt[d]++ -------
__global__ void agg_ent_kernel(const float* __restrict__ h, const float* __restrict__ relh,
                               const int* __restrict__ src, const int* __restrict__ dst,
                               const int* __restrict__ erel,
                               float* __restrict__ agg, float* __restrict__ cnt) {
  int wid = (blockIdx.x * blockDim.x + threadIdx.x) >> 6;
  int lane = threadIdx.x & 63;
  if (wid >= NE) return;
  int s = src[wid], d = dst[wid], r = erel[wid];
  const float* hr = h + (size_t)s * HD;
  const float* rr = relh + (size_t)r * HD;
  float* arow = agg + (size_t)d * HD;
  #pragma unroll
  for (int j = 0; j < 8; ++j) {
    int i = lane + 64 * j;
    atomicAdd(&arow[i], hr[i] + rr[i]);
  }
  if (lane == 0) atomicAdd(&cnt[d], 1.0f);
}

// ---------------- GRU elementwise (biases folded in here) ------------------
__global__ void gru_kernel(const float* __restrict__ gi, const float* __restrict__ gh,
                           const float* __restrict__ bih, const float* __restrict__ bhh,
                           float* __restrict__ relh) {
  int i = blockIdx.x * blockDim.x + threadIdx.x;
  if (i >= N_REL * HD) return;
  int row = i >> 9, col = i & 511;
  const float* gir = gi + (size_t)row * 1536;
  const float* ghr = gh + (size_t)row * 1536;
  float ir = gir[col] + bih[col];
  float iz = gir[col + 512] + bih[col + 512];
  float inn = gir[col + 1024] + bih[col + 1024];
  float hr = ghr[col] + bhh[col];
  float hz = ghr[col + 512] + bhh[col + 512];
  float hn = ghr[col + 1024] + bhh[col + 1024];
  float r = sigmoidf_(ir + hr);
  float z = sigmoidf_(iz + hz);
  float n = tanhf(inn + r * hn);
  relh[i] = (1.0f - z) * n + z * relh[i];
}

// ---------------- gather rows (f32) ----------------------------------------
__global__ void gather_kernel(const float* __restrict__ table, const int* __restrict__ idx,
                              float* __restrict__ out, int rows) {
  int i = blockIdx.x * blockDim.x + threadIdx.x;
  if (i >= rows * (HD / 4)) return;
  int row = i >> 7, q = i & 127;
  ((float4*)out)[i] = ((const float4*)(table + (size_t)idx[row] * HD))[q];
}

// ---------------- flat f32 -> bf16 convert (n multiple of 8) ---------------
__global__ void f2b_kernel(const float* __restrict__ in, unsigned short* __restrict__ out, int n) {
  int i = blockIdx.x * blockDim.x + threadIdx.x;
  if (i * 8 >= n) return;
  float4 a = *(const float4*)&in[i * 8];
  float4 b = *(const float4*)&in[i * 8 + 4];
  u16x8 pk = {f2bf(a.x), f2bf(a.y), f2bf(a.z), f2bf(a.w),
              f2bf(b.x), f2bf(b.y), f2bf(b.z), f2bf(b.w)};
  *(u16x8*)&out[i * 8] = pk;
}

// ---------------------------------------------------------------------------
// pack_nn: B (KxN f32 row-major) -> bf16 LDS-image layout:
// step s (32 k): idx = (s*N + n)*32 + ((g ^ ((n>>2)&3))<<3) + j  holds
// B[s*32 + g*8 + j][n].
// ---------------------------------------------------------------------------
__global__ void pack_nn_kernel(const float* __restrict__ B, unsigned short* __restrict__ out,
                               int K, int N) {
  int id = blockIdx.x * 256 + threadIdx.x;
  if (id >= (K >> 3) * N) return;
  int s = id / (N * 4);
  int rem = id - s * (N * 4);
  int n = rem >> 2, g = rem & 3;
  const float* src = B + (size_t)(s * 32 + g * 8) * N + n;
  u16x8 pk;
  #pragma unroll
  for (int j = 0; j < 8; ++j) pk[j] = f2bf(src[(size_t)j * N]);
  *(u16x8*)&out[((size_t)s * N + n) * 32 + ((g ^ ((n >> 2) & 3)) << 3)] = pk;
}

// ---------------------------------------------------------------------------
// bf16 NN GEMM with f32 A (converted during staging) and pre-packed B image.
// A = [A0 (M x K0) | A1 (M x K1)] concatenated along K (K0 % 64 == 0).
// SCALEA0: scale A0 rows by 1/max(cnt[row],1) during staging (seg-mean fold).
// ACT: 0 plain, 1 relu, 3 gate: u=sigmoid(acc+bias[n]); C=u*D+(1-u)*C.
// ---------------------------------------------------------------------------
template <int ACT, int SCALEA0>
__global__ __launch_bounds__(256, 2)
void gemm_nn_bf16(const float* __restrict__ A0, const float* __restrict__ A1,
                  int K0, int K1, const float* __restrict__ cntA,
                  const unsigned short* __restrict__ Bp,
                  const float* __restrict__ bias, const float* __restrict__ D,
                  float* __restrict__ C, int M, int N) {
  __shared__ unsigned short As[128 * 64];
  __shared__ unsigned short Bs[2 * 128 * 32];
  const int tid = threadIdx.x;
  const int lane = tid & 63;
  const int w = tid >> 6;
  const int wm = w >> 1, wn = w & 1;
  const int m0 = blockIdx.x * 128, n0 = blockIdx.y * 128;
  const int lr = lane & 15, lg = lane >> 4;
  const int K = K0 + K1;
  const int arow = tid >> 1;
  const int akh = (tid & 1) * 32;

  float s0 = 1.0f;
  if (SCALEA0 && m0 + arow < M) s0 = 1.0f / fmaxf(cntA[m0 + arow], 1.0f);

  f32x4 acc[4][4];
  #pragma unroll
  for (int i = 0; i < 4; ++i)
    #pragma unroll
    for (int j = 0; j < 4; ++j) acc[i][j] = (f32x4){0.f, 0.f, 0.f, 0.f};

  for (int k0 = 0; k0 < K; k0 += 64) {
    __syncthreads();
    {
      int mrow = m0 + arow;
      int kk = k0 + akh;
      const float* base; int stride, kloc;
      float sc;
      if (kk < K0) { base = A0; stride = K0; kloc = kk; sc = SCALEA0 ? s0 : 1.0f; }
      else         { base = A1; stride = K1; kloc = kk - K0; sc = 1.0f; }
      u16x8 pk[4];
      if (mrow < M) {
        const float* p = base + (size_t)mrow * stride + kloc;
        #pragma unroll
        for (int q = 0; q < 4; ++q) {
          float4 x = *(const float4*)(p + q * 8);
          float4 y = *(const float4*)(p + q * 8 + 4);
          pk[q] = (u16x8){f2bf(x.x * sc), f2bf(x.y * sc), f2bf(x.z * sc), f2bf(x.w * sc),
                          f2bf(y.x * sc), f2bf(y.y * sc), f2bf(y.z * sc), f2bf(y.w * sc)};
        }
      } else {
        #pragma unroll
        for (int q = 0; q < 4; ++q) pk[q] = (u16x8){0, 0, 0, 0, 0, 0, 0, 0};
      }
      #pragma unroll
      for (int q = 0; q < 4; ++q) {
        int chunk = (akh >> 3) + q;
        *(u16x8*)&As[arow * 64 + ((chunk ^ (arow & 7)) << 3)] = pk[q];
      }
    }
    {
      int s = k0 >> 5;
      #pragma unroll
      for (int sl = 0; sl < 2; ++sl) {
        const unsigned short* src = Bp + ((size_t)(s + sl) * N + n0) * 32;
        #pragma unroll
        for (int q = 0; q < 2; ++q) {
          int off = (q * 256 + tid) * 8;
          *(u16x8*)&Bs[sl * 4096 + off] = *(const u16x8*)&src[off];
        }
      }
    }
    __syncthreads();
    #pragma unroll
    for (int u = 0; u < 2; ++u) {
      bf16x8 a[4], b[4];
      #pragma unroll
      for (int i = 0; i < 4; ++i) {
        int r = wm * 64 + i * 16 + lr;
        a[i] = *(const bf16x8*)&As[r * 64 + (((u * 4 + lg) ^ (r & 7)) << 3)];
        int nl = wn * 64 + i * 16 + lr;
        b[i] = *(const bf16x8*)&Bs[u * 4096 + nl * 32 + ((lg ^ ((nl >> 2) & 3)) << 3)];
      }
      #pragma unroll
      for (int i = 0; i < 4; ++i)
        #pragma unroll
        for (int j = 0; j < 4; ++j)
          acc[i][j] = __builtin_amdgcn_mfma_f32_16x16x32_bf16(a[i], b[j], acc[i][j], 0, 0, 0);
    }
  }

  #pragma unroll
  for (int i = 0; i < 4; ++i) {
    int m = m0 + wm * 64 + i * 16 + lg * 4;
    #pragma unroll
    for (int j = 0; j < 4; ++j) {
      int n = n0 + wn * 64 + j * 16 + lr;
      #pragma unroll
      for (int q = 0; q < 4; ++q) {
        int mr = m + q;
        if (mr >= M) continue;
        size_t o = (size_t)mr * N + n;
        float v = acc[i][j][q];
        if (ACT == 0) {
          C[o] = v;
        } else if (ACT == 1) {
          C[o] = fmaxf(v, 0.0f);
        } else {
          float u_ = sigmoidf_(v + bias[n]);
          C[o] = u_ * D[o] + (1.0f - u_) * C[o];
        }
      }
    }
  }
}

// ---------------------------------------------------------------------------
// pack_fw: fw (32768x512 f32) -> bf16 image (same layout as pack_nn, N=512)
// ---------------------------------------------------------------------------
__global__ __launch_bounds__(256)
void pack_fw_kernel(const float* __restrict__ f0, const float* __restrict__ f1,
                    const float* __restrict__ f2, const float* __restrict__ f3,
                    unsigned short* __restrict__ o0, unsigned short* __restrict__ o1,
                    unsigned short* __restrict__ o2, unsigned short* __restrict__ o3) {
  __shared__ float L[32][512];
  const float* fw; unsigned short* op;
  switch (blockIdx.y) {
    case 0: fw = f0; op = o0; break;
    case 1: fw = f1; op = o1; break;
    case 2: fw = f2; op = o2; break;
    default: fw = f3; op = o3; break;
  }
  int s = blockIdx.x, tid = threadIdx.x;
  #pragma unroll
  for (int i = 0; i < 16; ++i) {
    int idx = tid + 256 * i;
    int r = idx >> 7, cq = (idx & 127) << 2;
    *(float4*)&L[r][cq] = *(const float4*)&fw[(size_t)(s * 32 + r) * 512 + cq];
  }
  __syncthreads();
  #pragma unroll
  for (int ii = 0; ii < 8; ++ii) {
    int slot = tid + 256 * ii;
    int n = slot >> 2, g = slot & 3;
    u16x8 pk;
    #pragma unroll
    for (int j = 0; j < 8; ++j) pk[j] = f2bf(L[g * 8 + j][n]);
    size_t off = (size_t)s * 16384 + n * 32 + ((g ^ ((n >> 2) & 3)) << 3);
    *(u16x8*)&op[off] = pk;
  }
}

// ---------------------------------------------------------------------------
// convgen: conv1d('SAME',K=3)+relu -> A_conv bf16 [NB][c*512+h], both paths.
// Thread = (b, h-octet); X window held in regs, looped over all 64 channels.
// X read once; stores coalesced across lanes (o fastest).
// ---------------------------------------------------------------------------
template <int CIN>
__global__ __launch_bounds__(256)
void convgen_kernel(const float* __restrict__ X0e, const float* __restrict__ X1e,
                    const float* __restrict__ X2e,
                    const float* __restrict__ cwE, const float* __restrict__ cbE,
                    const float* __restrict__ X0r, const float* __restrict__ X1r,
                    const float* __restrict__ X2r,
                    const float* __restrict__ cwR, const float* __restrict__ cbR,
                    unsigned short* __restrict__ Ae, unsigned short* __restrict__ Ar) {
  __shared__ float wsm[64 * CIN * 3];
  __shared__ float bsm[64];
  const int path = blockIdx.y;
  const float* X[CIN]; const float* cw; const float* cb; unsigned short* A;
  if (path == 0) {
    X[0] = X0e; X[1] = X1e; if constexpr (CIN == 3) X[2] = X2e;
    cw = cwE; cb = cbE; A = Ae;
  } else {
    X[0] = X0r; X[1] = X1r; if constexpr (CIN == 3) X[2] = X2r;
    cw = cwR; cb = cbR; A = Ar;
  }
  const int tid = threadIdx.x;
  for (int i = tid; i < 64 * CIN * 3; i += 256) wsm[i] = cw[i];
  if (tid < 64) bsm[tid] = cb[tid];
  __syncthreads();

  const int o = tid & 63;
  const int b = blockIdx.x * 4 + (tid >> 6);
  const int h = o * 8;

  float xm[CIN][8], xl[CIN], xr[CIN];
  #pragma unroll
  for (int ci = 0; ci < CIN; ++ci) {
    const float* row = X[ci] + (size_t)b * HD + h;
    float4 a4 = *(const float4*)row;
    float4 b4 = *(const float4*)(row + 4);
    xm[ci][0] = a4.x; xm[ci][1] = a4.y; xm[ci][2] = a4.z; xm[ci][3] = a4.w;
    xm[ci][4] = b4.x; xm[ci][5] = b4.y; xm[ci][6] = b4.z; xm[ci][7] = b4.w;
    xl[ci] = (h > 0) ? row[-1] : 0.f;
    xr[ci] = (h + 8 < HD) ? row[8] : 0.f;
  }
  unsigned short* dst = A + (size_t)b * 32768 + h;
  for (int c = 0; c < 64; ++c) {
    float v[8];
    float cbv = bsm[c];
    #pragma unroll
    for (int e = 0; e < 8; ++e) v[e] = cbv;
    #pragma unroll
    for (int ci = 0; ci < CIN; ++ci) {
      float w0 = wsm[(c * CIN + ci) * 3 + 0];
      float w1 = wsm[(c * CIN + ci) * 3 + 1];
      float w2 = wsm[(c * CIN + ci) * 3 + 2];
      #pragma unroll
      for (int e = 0; e < 8; ++e) {
        float lft = e ? xm[ci][e - 1] : xl[ci];
        float rgt = (e < 7) ? xm[ci][e + 1] : xr[ci];
        v[e] = fmaf(lft, w0, fmaf(xm[ci][e], w1, fmaf(rgt, w2, v[e])));
      }
    }
    u16x8 pk;
    #pragma unroll
    for (int e = 0; e < 8; ++e) pk[e] = f2bf(fmaxf(v[e], 0.f));
    *(u16x8*)&dst[c * 512] = pk;
  }
}

// ---------------------------------------------------------------------------
// gemm_fc: part[path][ks] = A_conv(4096 x 32768 bf16) @ fw-image, KSPLIT=4.
// Grid (32 m, 4 n, 8 z): path = z>>2, ks = z&3. Single-barrier double-buffered:
// per iter: gload(it+1)->regs | ds_read(cur)->frags | 32 MFMA | ds_write(cur^1)
// | barrier. LDS 64KB, 2 blocks/CU.
// ---------------------------------------------------------------------------
__global__ __launch_bounds__(256, 2)
void gemm_fc(const unsigned short* __restrict__ Abuf,
             const unsigned short* __restrict__ fwpE,
             const unsigned short* __restrict__ fwpR,
             float* __restrict__ partBase) {
  __shared__ unsigned short As[2][128 * 64];     // 2 x 16KB
  __shared__ unsigned short Bs[2][2 * 128 * 32]; // 2 x 16KB
  const int tid = threadIdx.x;
  const int lane = tid & 63;
  const int wv = tid >> 6;
  const int wm = wv >> 1, wn = wv & 1;
  const int lr = lane & 15, lg = lane >> 4;
  const int m0 = blockIdx.x * 128;
  const int n0 = blockIdx.y * 128;
  const int path = blockIdx.z >> 2;
  const int ks = blockIdx.z & 3;

  const unsigned short* A = Abuf + (size_t)path * ((size_t)NB * 32768);
  const unsigned short* fwp = (path == 0) ? fwpE : fwpR;
  float* part = partBase + (size_t)(path * 4 + ks) * ((size_t)NB * HD);

  const int arow = tid >> 1;
  const int achunk = (tid & 1) * 4;              // chunk base (0 or 4) = k-half/8
  const unsigned short* aRow = A + (size_t)(m0 + arow) * 32768 + ks * 8192 + achunk * 8;
  const unsigned short* bBase = fwp + (size_t)(ks * 256) * 16384 + (size_t)n0 * 32;

  f32x4 acc[4][4];
  #pragma unroll
  for (int i = 0; i < 4; ++i)
    #pragma unroll
    for (int j = 0; j < 4; ++j) acc[i][j] = (f32x4){0.f, 0.f, 0.f, 0.f};

  auto gload = [&](int it, u16x8* ar, u16x8* br) {
    const unsigned short* ap = aRow + it * 64;
    #pragma unroll
    for (int q = 0; q < 4; ++q) ar[q] = *(const u16x8*)&ap[q * 8];
    const unsigned short* bp = bBase + (size_t)it * 2 * 16384;
    br[0] = *(const u16x8*)&bp[tid * 8];
    br[1] = *(const u16x8*)&bp[2048 + tid * 8];
    br[2] = *(const u16x8*)&bp[16384 + tid * 8];
    br[3] = *(const u16x8*)&bp[16384 + 2048 + tid * 8];
  };
  auto swrite = [&](int nb, const u16x8* ar, const u16x8* br) {
    #pragma unroll
    for (int q = 0; q < 4; ++q) {
      int chunk = achunk + q;
      *(u16x8*)&As[nb][arow * 64 + ((chunk ^ (arow & 7)) << 3)] = ar[q];
    }
    *(u16x8*)&Bs[nb][tid * 8] = br[0];
    *(u16x8*)&Bs[nb][2048 + tid * 8] = br[1];
    *(u16x8*)&Bs[nb][4096 + tid * 8] = br[2];
    *(u16x8*)&Bs[nb][4096 + 2048 + tid * 8] = br[3];
  };

  {  // prologue
    u16x8 ar[4], br[4];
    gload(0, ar, br);
    swrite(0, ar, br);
  }
  __syncthreads();

  int cur = 0;
  for (int it = 0; it < 128; ++it) {
    u16x8 ar[4], br[4];
    if (it < 127) gload(it + 1, ar, br);
    bf16x8 af[2][4], bfr[2][4];
    #pragma unroll
    for (int u = 0; u < 2; ++u)
      #pragma unroll
      for (int i = 0; i < 4; ++i) {
        int r = wm * 64 + i * 16 + lr;
        af[u][i] = *(const bf16x8*)&As[cur][r * 64 + (((u * 4 + lg) ^ (r & 7)) << 3)];
        int nl = wn * 64 + i * 16 + lr;
        bfr[u][i] = *(const bf16x8*)&Bs[cur][u * 4096 + nl * 32 + ((lg ^ ((nl >> 2) & 3)) << 3)];
      }
    #pragma unroll
    for (int u = 0; u < 2; ++u)
      #pragma unroll
      for (int i = 0; i < 4; ++i)
        #pragma unroll
        for (int j = 0; j < 4; ++j)
          acc[i][j] = __builtin_amdgcn_mfma_f32_16x16x32_bf16(af[u][i], bfr[u][j], acc[i][j], 0, 0, 0);
    if (it < 127) swrite(cur ^ 1, ar, br);
    __syncthreads();
    cur ^= 1;
  }

  #pragma unroll
  for (int i = 0; i < 4; ++i) {
    int m = m0 + wm * 64 + i * 16 + lg * 4;
    #pragma unroll
    for (int j = 0; j < 4; ++j) {
      int n = n0 + wn * 64 + j * 16 + lr;
      #pragma unroll
      for (int q = 0; q < 4; ++q)
        part[(size_t)(m + q) * HD + n] = acc[i][j][q];
    }
  }
}

// ---------------------------------------------------------------------------
// reduce 4 split-K partials + bias + relu -> f32 out AND bf16 out
// ---------------------------------------------------------------------------
__global__ void reduce4_kernel(const float* __restrict__ pE, const float* __restrict__ pR,
                               const float* __restrict__ bE, const float* __restrict__ bR,
                               float* __restrict__ oE, float* __restrict__ oR,
                               unsigned short* __restrict__ obE, unsigned short* __restrict__ obR) {
  int p = blockIdx.y;
  const float* part = p ? pR : pE;
  const float* bias = p ? bR : bE;
  float* o = p ? oR : oE;
  unsigned short* ob = p ? obR : obE;
  int i = blockIdx.x * 256 + threadIdx.x;
  int col = (i << 2) & 511;
  float4 s = *(const float4*)&part[(size_t)i * 4];
  #pragma unroll
  for (int ks = 1; ks < 4; ++ks) {
    float4 t = *(const float4*)&part[(size_t)ks * (NB * HD) + i * 4];
    s.x += t.x; s.y += t.y; s.z += t.z; s.w += t.w;
  }
  float4 b4 = *(const float4*)&bias[col];
  s.x = fmaxf(s.x + b4.x, 0.f); s.y = fmaxf(s.y + b4.y, 0.f);
  s.z = fmaxf(s.z + b4.z, 0.f); s.w = fmaxf(s.w + b4.w, 0.f);
  *(float4*)&o[(size_t)i * 4] = s;
  u16x4 pk = {f2bf(s.x), f2bf(s.y), f2bf(s.z), f2bf(s.w)};
  *(u16x4*)&ob[(size_t)i * 4] = pk;
}

// ---------------------------------------------------------------------------
// bf16 NT GEMM: C(MxN, f32) = A(MxK) @ B(NxK)^T, both bf16 row-major.
// ---------------------------------------------------------------------------
__global__ __launch_bounds__(256, 3)
void gemm_nt_bf16(const unsigned short* __restrict__ A, const unsigned short* __restrict__ B,
                  float* __restrict__ C, int M, int N, int K) {
  __shared__ unsigned short As[128 * 64];
  __shared__ unsigned short Bs[128 * 64];
  const int tid = threadIdx.x;
  const int lane = tid & 63;
  const int w = tid >> 6;
  const int wm = w >> 1, wn = w & 1;
  const int m0 = blockIdx.x * 128, n0 = blockIdx.y * 128;
  const int lr = lane & 15, lg = lane >> 4;

  f32x4 acc[4][4];
  #pragma unroll
  for (int i = 0; i < 4; ++i)
    #pragma unroll
    for (int j = 0; j < 4; ++j) acc[i][j] = (f32x4){0.f, 0.f, 0.f, 0.f};

  for (int k0 = 0; k0 < K; k0 += 64) {
    __syncthreads();
    {
      int row = tid >> 1, half = tid & 1;
      const unsigned short* asrc = A + (size_t)(m0 + row) * K + k0 + half * 32;
      #pragma unroll
      for (int q = 0; q < 4; ++q) {
        int chunk = half * 4 + q;
        *(u16x8*)&As[row * 64 + (chunk ^ (row & 7)) * 8] = *(const u16x8*)&asrc[q * 8];
      }
      int nrow = n0 + row;
      const unsigned short* bsrc = B + (size_t)nrow * K + k0 + half * 32;
      u16x8 z = {0, 0, 0, 0, 0, 0, 0, 0};
      #pragma unroll
      for (int q = 0; q < 4; ++q) {
        int chunk = half * 4 + q;
        u16x8 v = (nrow < N) ? *(const u16x8*)&bsrc[q * 8] : z;
        *(u16x8*)&Bs[row * 64 + (chunk ^ (row & 7)) * 8] = v;
      }
    }
    __syncthreads();
    #pragma unroll
    for (int u = 0; u < 2; ++u) {
      bf16x8 a[4], b[4];
      #pragma unroll
      for (int i = 0; i < 4; ++i) {
        int r = wm * 64 + i * 16 + lr;
        a[i] = *(const bf16x8*)&As[r * 64 + (((u * 4 + lg) ^ (r & 7))) * 8];
        int n = wn * 64 + i * 16 + lr;
        b[i] = *(const bf16x8*)&Bs[n * 64 + (((u * 4 + lg) ^ (n & 7))) * 8];
      }
      #pragma unroll
      for (int i = 0; i < 4; ++i)
        #pragma unroll
        for (int j = 0; j < 4; ++j)
          acc[i][j] = __builtin_amdgcn_mfma_f32_16x16x32_bf16(a[i], b[j], acc[i][j], 0, 0, 0);
    }
  }

  #pragma unroll
  for (int i = 0; i < 4; ++i) {
    int m = m0 + wm * 64 + i * 16 + lg * 4;
    #pragma unroll
    for (int j = 0; j < 4; ++j) {
      int n = n0 + wn * 64 + j * 16 + lr;
      if (n < N) {
        #pragma unroll
        for (int q = 0; q < 4; ++q)
          C[(size_t)(m + q) * N + n] = acc[i][j][q];
      }
    }
  }
}

// ---------------------------------------------------------------------------
extern "C" void kernel_launch(void* const* d_in, const int* in_sizes, int n_in,
                              void* d_out, int out_size, void* d_ws, size_t ws_size,
                              hipStream_t stream) {
  const float* ent_embeds = (const float*)d_in[0];
  const float* rel_embeds = (const float*)d_in[1];
  const float* W_msg  = (const float*)d_in[2];
  const float* W_self = (const float*)d_in[3];
  const float* gru_Wih = (const float*)d_in[4];
  const float* gru_Whh = (const float*)d_in[5];
  const float* gru_bih = (const float*)d_in[6];
  const float* gru_bhh = (const float*)d_in[7];
  const float* gate_W = (const float*)d_in[8];
  const float* gate_b = (const float*)d_in[9];
  const float* e_conv1 = (const float*)d_in[10]; const float* e_cb1 = (const float*)d_in[11];
  const float* e_fc1   = (const float*)d_in[12]; const float* e_fb1 = (const float*)d_in[13];
  const float* e_conv2 = (const float*)d_in[14]; const float* e_cb2 = (const float*)d_in[15];
  const float* e_fc2   = (const float*)d_in[16]; const float* e_fb2 = (const float*)d_in[17];
  const float* r_conv1 = (const float*)d_in[18]; const float* r_cb1 = (const float*)d_in[19];
  const float* r_fc1   = (const float*)d_in[20]; const float* r_fb1 = (const float*)d_in[21];
  const float* r_conv2 = (const float*)d_in[22]; const float* r_cb2 = (const float*)d_in[23];
  const float* r_fc2   = (const float*)d_in[24]; const float* r_fb2 = (const float*)d_in[25];
  const int* src  = (const int*)d_in[26];
  const int* dst  = (const int*)d_in[27];
  const int* erel = (const int*)d_in[28];
  const int* subj = (const int*)d_in[29];
  const int* rel  = (const int*)d_in[30];
  const int* obj  = (const int*)d_in[31];
  float* out = (float*)d_out;

  // -------- workspace layout --------
  float* w = (float*)d_ws;
  float* ent   = w; w += (size_t)N_ENT * HD;
  float* relh  = w; w += (size_t)N_REL * HD;
  float* aggR  = w; w += (size_t)N_REL * HD;
  float* cntR  = w; w += N_REL;
  float* gi    = w; w += (size_t)N_REL * 1536;
  float* gh    = w; w += (size_t)N_REL * 1536;
  float* aggE  = w; w += (size_t)N_ENT * HD;     // } aggE..h1b reused post-loop as
  float* cntE  = w; w += N_ENT;                  // } packed-fw storage
  float* tmp   = w; w += (size_t)N_ENT * HD;
  float* h0b   = w; w += (size_t)N_ENT * HD;
  float* h1b   = w; w += (size_t)N_ENT * HD;
  float* se    = w; w += (size_t)NB * HD;
  float* re_   = w; w += (size_t)NB * HD;
  float* oe    = w; w += (size_t)NB * HD;
  float* o1    = w; w += (size_t)NB * HD;
  float* q1    = w; w += (size_t)NB * HD;
  float* o2    = w; w += (size_t)NB * HD;
  float* q2    = w; w += (size_t)NB * HD;
  unsigned short* ent_bf = (unsigned short*)w; w += (size_t)N_ENT * HD / 2;
  unsigned short* relh_bf = (unsigned short*)w; w += (size_t)N_REL * HD / 2;
  unsigned short* o1b = (unsigned short*)w; w += (size_t)NB * HD / 2;
  unsigned short* q1b = (unsigned short*)w; w += (size_t)NB * HD / 2;
  unsigned short* o2b = (unsigned short*)w; w += (size_t)NB * HD / 2;
  unsigned short* q2b = (unsigned short*)w; w += (size_t)NB * HD / 2;
  // recurrence weight packs (bf16), live across the whole call
  unsigned short* wp_ih = (unsigned short*)w;    // 1024x1536
  unsigned short* wp_hh = wp_ih + (size_t)1024 * 1536;
  unsigned short* wp_l0 = wp_hh + (size_t)512 * 1536;
  unsigned short* wp_l1 = wp_l0 + (size_t)1024 * 512;
  unsigned short* wp_g  = wp_l1 + (size_t)1024 * 512;
  // fw packs alias the recurrence temporaries (used only post-loop)
  unsigned short* fwp0 = (unsigned short*)aggE;
  unsigned short* fwp1 = fwp0 + (size_t)16777216;
  unsigned short* fwp2 = fwp1 + (size_t)16777216;
  unsigned short* fwp3 = fwp2 + (size_t)16777216;
  (void)tmp; (void)h0b;
  // decoder scratch in d_out (all written+consumed before logits):
  // A_conv: 2 paths x NB x 32768 u16 = f32 [0, 134217728)
  unsigned short* Abuf = (unsigned short*)out;
  // split-K partials: f32 [134217728, 150994944)  (out_size = 165937152)
  float* pE = out + (size_t)134217728;
  float* pR = pE + (size_t)4 * NB * HD;

  const dim3 g_gru(2, 12);     // 256 x 1536
  const dim3 g_ent(157, 4);    // 20000 x 512

  // -------- weight packing (once) --------
  {
    int t;
    t = (1024 * 1536) / 8; pack_nn_kernel<<<(t + 255) / 256, 256, 0, stream>>>(gru_Wih, wp_ih, 1024, 1536);
    t = (512 * 1536) / 8;  pack_nn_kernel<<<(t + 255) / 256, 256, 0, stream>>>(gru_Whh, wp_hh, 512, 1536);
    t = (512 * 512) / 8;
    pack_nn_kernel<<<(t + 255) / 256, 256, 0, stream>>>(W_msg, wp_l0, 512, 512);
    pack_nn_kernel<<<(t + 255) / 256, 256, 0, stream>>>(W_self, wp_l0 + (size_t)512 * 512, 512, 512);
    pack_nn_kernel<<<(t + 255) / 256, 256, 0, stream>>>(W_msg + (size_t)512 * 512, wp_l1, 512, 512);
    pack_nn_kernel<<<(t + 255) / 256, 256, 0, stream>>>(W_self + (size_t)512 * 512, wp_l1 + (size_t)512 * 512, 512, 512);
    pack_nn_kernel<<<(t + 255) / 256, 256, 0, stream>>>(gate_W, wp_g, 512, 512);
  }

  // -------- init --------
  rownorm_kernel<<<N_ENT / 4, 256, 0, stream>>>(ent_embeds, ent, N_ENT);
  hipMemcpyAsync(relh, rel_embeds, (size_t)N_REL * HD * 4, hipMemcpyDeviceToDevice, stream);

  // -------- timestep loop --------
  for (int t = 0; t < NT; ++t) {
    const int* st = src + t * NE;
    const int* dt = dst + t * NE;
    const int* rt = erel + t * NE;

    hipMemsetAsync(aggR, 0, ((size_t)N_REL * HD + N_REL) * 4, stream);
    agg_rel_kernel<<<NE / 4, 256, 0, stream>>>(ent, st, rt, aggR, cntR);
    gemm_nn_bf16<0, 1><<<g_gru, 256, 0, stream>>>(aggR, rel_embeds, 512, 512, cntR, wp_ih,
                                                  nullptr, nullptr, gi, N_REL, 1536);
    gemm_nn_bf16<0, 0><<<g_gru, 256, 0, stream>>>(relh, relh, 512, 0, nullptr, wp_hh,
                                                  nullptr, nullptr, gh, N_REL, 1536);
    gru_kernel<<<(N_REL * HD) / 256, 256, 0, stream>>>(gi, gh, gru_bih, gru_bhh, relh);

    const float* hcur = ent;
    float* bufs[2] = {h0b, h1b};
    const unsigned short* wls[2] = {wp_l0, wp_l1};
    for (int l = 0; l < 2; ++l) {
      hipMemsetAsync(aggE, 0, ((size_t)N_ENT * HD + N_ENT) * 4, stream);
      agg_ent_kernel<<<NE / 4, 256, 0, stream>>>(hcur, relh, st, dt, rt, aggE, cntE);
      gemm_nn_bf16<1, 1><<<g_ent, 256, 0, stream>>>(aggE, hcur, 512, 512, cntE, wls[l],
                                                    nullptr, nullptr, bufs[l], N_ENT, 512);
      hcur = bufs[l];
    }
    rownorm_kernel<<<N_ENT / 4, 256, 0, stream>>>(h1b, h1b, N_ENT);
    gemm_nn_bf16<3, 0><<<g_ent, 256, 0, stream>>>(h1b, h1b, 512, 0, nullptr, wp_g,
                                                  gate_b, h1b, ent, N_ENT, 512);
  }

  // -------- decoder prep --------
  pack_fw_kernel<<<dim3(1024, 4), 256, 0, stream>>>(e_fc1, r_fc1, e_fc2, r_fc2,
                                                    fwp0, fwp1, fwp2, fwp3);
  f2b_kernel<<<(N_ENT * HD / 8) / 256, 256, 0, stream>>>(ent, ent_bf, N_ENT * HD);
  f2b_kernel<<<(N_REL * HD / 8) / 256, 256, 0, stream>>>(relh, relh_bf, N_REL * HD);
  gather_kernel<<<(NB * HD / 4) / 256, 256, 0, stream>>>(ent, subj, se, NB);
  gather_kernel<<<(NB * HD / 4) / 256, 256, 0, stream>>>(relh, rel, re_, NB);
  gather_kernel<<<(NB * HD / 4) / 256, 256, 0, stream>>>(ent, obj, oe, NB);

  unsigned short* A_E = Abuf;
  unsigned short* A_R = Abuf + (size_t)NB * 32768;

  // -------- decoder stage 1 --------
  convgen_kernel<2><<<dim3(NB / 4, 2), 256, 0, stream>>>(
      se, re_, nullptr, e_conv1, e_cb1,
      se, oe, nullptr, r_conv1, r_cb1, A_E, A_R);
  gemm_fc<<<dim3(32, 4, 8), 256, 0, stream>>>(Abuf, fwp0, fwp1, pE);
  reduce4_kernel<<<dim3(NB * HD / 4 / 256, 2), 256, 0, stream>>>(
      pE, pR, e_fb1, r_fb1, o1, q1, o1b, q1b);

  // -------- decoder stage 2 --------
  convgen_kernel<3><<<dim3(NB / 4, 2), 256, 0, stream>>>(
      o1, se, re_, e_conv2, e_cb2,
      q1, se, oe, r_conv2, r_cb2, A_E, A_R);
  gemm_fc<<<dim3(32, 4, 8), 256, 0, stream>>>(Abuf, fwp2, fwp3, pE);
  reduce4_kernel<<<dim3(NB * HD / 4 / 256, 2), 256, 0, stream>>>(
      pE, pR, e_fb2, r_fb2, o2, q2, o2b, q2b);

  // -------- logits (bf16 MFMA) --------
  size_t off0 = 0;
  size_t off1 = (size_t)NB * N_ENT;
  size_t off2 = off1 + (size_t)NB * N_REL;
  size_t off3 = off2 + (size_t)NB * N_ENT;
  gemm_nt_bf16<<<dim3(32, 157), 256, 0, stream>>>(o1b, ent_bf, out + off0, NB, N_ENT, HD);
  gemm_nt_bf16<<<dim3(32, 2), 256, 0, stream>>>(q1b, relh_bf, out + off1, NB, N_REL, HD);
  gemm_nt_bf16<<<dim3(32, 157), 256, 0, stream>>>(o2b, ent_bf, out + off2, NB, N_ENT, HD);
  gemm_nt_bf16<<<dim3(32, 2), 256, 0, stream>>>(q2b, relh_bf, out + off3, NB, N_REL, HD);
}

// Round 6
// 5289.577 us; speedup vs baseline: 1.4516x; 1.0379x over previous
//
#include <hip/hip_runtime.h>
#include <math.h>

// ---------------------------------------------------------------------------
// Refine (RE-GCN style): bf16-MFMA recurrence + decoder; f32 state with
// maintained bf16 mirrors (A-staging = identity copy, no per-GEMM convert).
// N_ENT=20000 N_REL=256 H=512 C=64 K=3 L=2 T=8 E=30000 B=4096
// ---------------------------------------------------------------------------

#define N_ENT 20000
#define N_REL 256
#define HD    512
#define NE    30000
#define NB    4096
#define NT    8

typedef __attribute__((ext_vector_type(8))) short          bf16x8;
typedef __attribute__((ext_vector_type(4))) float          f32x4;
typedef __attribute__((ext_vector_type(8))) unsigned short u16x8;
typedef __attribute__((ext_vector_type(4))) unsigned short u16x4;

static __device__ __forceinline__ float sigmoidf_(float x) {
  return 1.0f / (1.0f + expf(-x));
}
static __device__ __forceinline__ unsigned short f2bf(float f) {  // RNE
  unsigned u = __float_as_uint(f);
  return (unsigned short)((u + 0x7FFFu + ((u >> 16) & 1u)) >> 16);
}

// ---------------- row L2 normalize + bf16 mirror ---------------------------
__global__ void rownorm_kernel(const float* __restrict__ in, float* __restrict__ out,
                               unsigned short* __restrict__ outb, int rows) {
  int wid = (blockIdx.x * blockDim.x + threadIdx.x) >> 6;
  int lane = threadIdx.x & 63;
  if (wid >= rows) return;
  const float4* ip = (const float4*)(in + (size_t)wid * HD);
  float4 v0 = ip[lane];
  float4 v1 = ip[lane + 64];
  float s = v0.x * v0.x + v0.y * v0.y + v0.z * v0.z + v0.w * v0.w
          + v1.x * v1.x + v1.y * v1.y + v1.z * v1.z + v1.w * v1.w;
  #pragma unroll
  for (int m = 1; m < 64; m <<= 1) s += __shfl_xor(s, m);
  float inv = 1.0f / (sqrtf(s) + 1e-8f);
  float4* op = (float4*)(out + (size_t)wid * HD);
  v0.x *= inv; v0.y *= inv; v0.z *= inv; v0.w *= inv;
  v1.x *= inv; v1.y *= inv; v1.z *= inv; v1.w *= inv;
  op[lane] = v0; op[lane + 64] = v1;
  unsigned short* ob = outb + (size_t)wid * HD;
  u16x4 p0 = {f2bf(v0.x), f2bf(v0.y), f2bf(v0.z), f2bf(v0.w)};
  u16x4 p1 = {f2bf(v1.x), f2bf(v1.y), f2bf(v1.z), f2bf(v1.w)};
  *(u16x4*)&ob[lane * 4] = p0;
  *(u16x4*)&ob[(lane + 64) * 4] = p1;
}

// ---------------- relation aggregation: agg[r] += ent[s], cnt[r]++ ----------
__global__ void agg_rel_kernel(const float* __restrict__ ent, const int* __restrict__ src,
                               const int* __restrict__ erel,
                               float* __restrict__ agg, float* __restrict__ cnt) {
  int wid = (blockIdx.x * blockDim.x + threadIdx.x) >> 6;
  int lane = threadIdx.x & 63;
  if (wid >= NE) return;
  int s = src[wid], r = erel[wid];
  const float* row = ent + (size_t)s * HD;
  float* arow = agg + (size_t)r * HD;
  #pragma unroll
  for (int j = 0; j < 8; ++j) atomicAdd(&arow[lane + 64 * j], row[lane + 64 * j]);
  if (lane == 0) atomicAdd(&cnt[r], 1.0f);
}

// ------------- entity aggregation: agg[d] += h[s] + relh[r], cnt[d]++ -------
__global__ void agg_ent_kernel(const float* __restrict__ h, const float* __restrict__ relh,
                               const int* __restrict__ src, const int* __restrict__ dst,
                               const int* __restrict__ erel,
                               float* __restrict__ agg, float* __restrict__ cnt) {
  int wid = (blockIdx.x * blockDim.x + threadIdx.x) >> 6;
  int lane = threadIdx.x & 63;
  if (wid >= NE) return;
  int s = src[wid], d = dst[wid], r = erel[wid];
  const float* hr = h + (size_t)s * HD;
  const float* rr = relh + (size_t)r * HD;
  float* arow = agg + (size_t)d * HD;
  #pragma unroll
  for (int j = 0; j < 8; ++j) {
    int i = lane + 64 * j;
    atomicAdd(&arow[i], hr[i] + rr[i]);
  }
  if (lane == 0) atomicAdd(&cnt[d], 1.0f);
}

// ---------------- GRU elementwise (+bias fold, +bf16 mirror) ---------------
__global__ void gru_kernel(const float* __restrict__ gi, const float* __restrict__ gh,
                           const float* __restrict__ bih, const float* __restrict__ bhh,
                           float* __restrict__ relh, unsigned short* __restrict__ relhb) {
  int i = blockIdx.x * blockDim.x + threadIdx.x;
  if (i >= N_REL * HD) return;
  int row = i >> 9, col = i & 511;
  const float* gir = gi + (size_t)row * 1536;
  const float* ghr = gh + (size_t)row * 1536;
  float ir = gir[col] + bih[col];
  float iz = gir[col + 512] + bih[col + 512];
  float inn = gir[col + 1024] + bih[col + 1024];
  float hr = ghr[col] + bhh[col];
  float hz = ghr[col + 512] + bhh[col + 512];
  float hn = ghr[col + 1024] + bhh[col + 1024];
  float r = sigmoidf_(ir + hr);
  float z = sigmoidf_(iz + hz);
  float n = tanhf(inn + r * hn);
  float v = (1.0f - z) * n + z * relh[i];
  relh[i] = v;
  relhb[i] = f2bf(v);
}

// ---------------- gather rows (f32) ----------------------------------------
__global__ void gather_kernel(const float* __restrict__ table, const int* __restrict__ idx,
                              float* __restrict__ out, int rows) {
  int i = blockIdx.x * blockDim.x + threadIdx.x;
  if (i >= rows * (HD / 4)) return;
  int row = i >> 7, q = i & 127;
  ((float4*)out)[i] = ((const float4*)(table + (size_t)idx[row] * HD))[q];
}

// ---------------- flat f32 -> bf16 convert (n multiple of 8) ---------------
__global__ void f2b_kernel(const float* __restrict__ in, unsigned short* __restrict__ out, int n) {
  int i = blockIdx.x * blockDim.x + threadIdx.x;
  if (i * 8 >= n) return;
  float4 a = *(const float4*)&in[i * 8];
  float4 b = *(const float4*)&in[i * 8 + 4];
  u16x8 pk = {f2bf(a.x), f2bf(a.y), f2bf(a.z), f2bf(a.w),
              f2bf(b.x), f2bf(b.y), f2bf(b.z), f2bf(b.w)};
  *(u16x8*)&out[i * 8] = pk;
}

// ---------------------------------------------------------------------------
// pack_nn: B (KxN f32 row-major) -> bf16 LDS-image layout:
// step s (32 k): idx = (s*N + n)*32 + ((g ^ ((n>>2)&3))<<3) + j  holds
// B[s*32 + g*8 + j][n].
// ---------------------------------------------------------------------------
__global__ void pack_nn_kernel(const float* __restrict__ B, unsigned short* __restrict__ out,
                               int K, int N) {
  int id = blockIdx.x * 256 + threadIdx.x;
  if (id >= (K >> 3) * N) return;
  int s = id / (N * 4);
  int rem = id - s * (N * 4);
  int n = rem >> 2, g = rem & 3;
  const float* src = B + (size_t)(s * 32 + g * 8) * N + n;
  u16x8 pk;
  #pragma unroll
  for (int j = 0; j < 8; ++j) pk[j] = f2bf(src[(size_t)j * N]);
  *(u16x8*)&out[((size_t)s * N + n) * 32 + ((g ^ ((n >> 2) & 3)) << 3)] = pk;
}

// ---------------------------------------------------------------------------
// GEMM core: single-barrier double-buffered bf16 MFMA GEMM vs packed B image.
// A = [A0 (Mx K0, f32, row-scaled by 1/max(cnt,1)) | A1 (M x K1, bf16)].
// ACT: 0 plain, 1 relu(+mirror), 3 gate: u=sigmoid(v+bias[n]); C=u*D+(1-u)*C.
// LDS passed in (2x16KB A, 2x16KB B). BM=BN=128, BK=64, 2x2 waves.
// ---------------------------------------------------------------------------
template <int ACT, int MIRROR>
static __device__ __forceinline__
void gemm_core(const float* __restrict__ A0, int K0, const float* __restrict__ cntA,
               const unsigned short* __restrict__ A1, int K1,
               const unsigned short* __restrict__ Bp,
               const float* __restrict__ bias, const float* __restrict__ D,
               float* __restrict__ C, unsigned short* __restrict__ Cb,
               int M, int N, int m0, int n0,
               unsigned short (*As)[8192], unsigned short (*Bs)[8192]) {
  const int tid = threadIdx.x;
  const int lane = tid & 63;
  const int wv = tid >> 6;
  const int wm = wv >> 1, wn = wv & 1;
  const int lr = lane & 15, lg = lane >> 4;
  const int arow = tid >> 1;
  const int akh = (tid & 1) * 32;
  const int achunk = (tid & 1) * 4;
  const int NIT = (K0 + K1) >> 6;

  float s0 = 1.0f;
  if (K0 > 0 && (m0 + arow) < M) s0 = 1.0f / fmaxf(cntA[m0 + arow], 1.0f);

  f32x4 acc[4][4];
  #pragma unroll
  for (int i = 0; i < 4; ++i)
    #pragma unroll
    for (int j = 0; j < 4; ++j) acc[i][j] = (f32x4){0.f, 0.f, 0.f, 0.f};

  auto gload = [&](int it, u16x8* ar, u16x8* br) {
    int mrow = m0 + arow;
    int kk = it * 64 + akh;
    if (mrow < M) {
      if (kk < K0) {
        const float* p = A0 + (size_t)mrow * K0 + kk;
        #pragma unroll
        for (int q = 0; q < 4; ++q) {
          float4 x = *(const float4*)(p + q * 8);
          float4 y = *(const float4*)(p + q * 8 + 4);
          ar[q] = (u16x8){f2bf(x.x * s0), f2bf(x.y * s0), f2bf(x.z * s0), f2bf(x.w * s0),
                          f2bf(y.x * s0), f2bf(y.y * s0), f2bf(y.z * s0), f2bf(y.w * s0)};
        }
      } else {
        const unsigned short* p = A1 + (size_t)mrow * K1 + (kk - K0);
        #pragma unroll
        for (int q = 0; q < 4; ++q) ar[q] = *(const u16x8*)&p[q * 8];
      }
    } else {
      #pragma unroll
      for (int q = 0; q < 4; ++q) ar[q] = (u16x8){0, 0, 0, 0, 0, 0, 0, 0};
    }
    const unsigned short* b0 = Bp + ((size_t)(2 * it) * N + n0) * 32;
    const unsigned short* b1 = Bp + ((size_t)(2 * it + 1) * N + n0) * 32;
    br[0] = *(const u16x8*)&b0[tid * 8];
    br[1] = *(const u16x8*)&b0[2048 + tid * 8];
    br[2] = *(const u16x8*)&b1[tid * 8];
    br[3] = *(const u16x8*)&b1[2048 + tid * 8];
  };
  auto swrite = [&](int nb, const u16x8* ar, const u16x8* br) {
    #pragma unroll
    for (int q = 0; q < 4; ++q) {
      int chunk = achunk + q;
      *(u16x8*)&As[nb][arow * 64 + ((chunk ^ (arow & 7)) << 3)] = ar[q];
    }
    *(u16x8*)&Bs[nb][tid * 8] = br[0];
    *(u16x8*)&Bs[nb][2048 + tid * 8] = br[1];
    *(u16x8*)&Bs[nb][4096 + tid * 8] = br[2];
    *(u16x8*)&Bs[nb][4096 + 2048 + tid * 8] = br[3];
  };

  {
    u16x8 ar[4], br[4];
    gload(0, ar, br);
    swrite(0, ar, br);
  }
  __syncthreads();

  int cur = 0;
  for (int it = 0; it < NIT; ++it) {
    u16x8 ar[4], br[4];
    if (it + 1 < NIT) gload(it + 1, ar, br);
    bf16x8 af[2][4], bfr[2][4];
    #pragma unroll
    for (int u = 0; u < 2; ++u)
      #pragma unroll
      for (int i = 0; i < 4; ++i) {
        int r = wm * 64 + i * 16 + lr;
        af[u][i] = *(const bf16x8*)&As[cur][r * 64 + (((u * 4 + lg) ^ (r & 7)) << 3)];
        int nl = wn * 64 + i * 16 + lr;
        bfr[u][i] = *(const bf16x8*)&Bs[cur][u * 4096 + nl * 32 + ((lg ^ ((nl >> 2) & 3)) << 3)];
      }
    #pragma unroll
    for (int u = 0; u < 2; ++u)
      #pragma unroll
      for (int i = 0; i < 4; ++i)
        #pragma unroll
        for (int j = 0; j < 4; ++j)
          acc[i][j] = __builtin_amdgcn_mfma_f32_16x16x32_bf16(af[u][i], bfr[u][j], acc[i][j], 0, 0, 0);
    if (it + 1 < NIT) swrite(cur ^ 1, ar, br);
    __syncthreads();
    cur ^= 1;
  }

  #pragma unroll
  for (int i = 0; i < 4; ++i) {
    int m = m0 + wm * 64 + i * 16 + lg * 4;
    #pragma unroll
    for (int j = 0; j < 4; ++j) {
      int n = n0 + wn * 64 + j * 16 + lr;
      #pragma unroll
      for (int q = 0; q < 4; ++q) {
        int mr = m + q;
        if (mr >= M) continue;
        size_t o = (size_t)mr * N + n;
        float v = acc[i][j][q];
        if (ACT == 0) {
          C[o] = v;
        } else if (ACT == 1) {
          float r = fmaxf(v, 0.0f);
          C[o] = r;
          if (MIRROR) Cb[o] = f2bf(r);
        } else {
          float u_ = sigmoidf_(v + bias[n]);
          float r = u_ * D[o] + (1.0f - u_) * C[o];
          C[o] = r;
          if (MIRROR) Cb[o] = f2bf(r);
        }
      }
    }
  }
}

template <int ACT, int MIRROR>
__global__ __launch_bounds__(256, 2)
void gemm_nn2(const float* __restrict__ A0, int K0, const float* __restrict__ cntA,
              const unsigned short* __restrict__ A1, int K1,
              const unsigned short* __restrict__ Bp,
              const float* __restrict__ bias, const float* __restrict__ D,
              float* __restrict__ C, unsigned short* __restrict__ Cb, int M, int N) {
  __shared__ unsigned short As[2][8192];
  __shared__ unsigned short Bs[2][8192];
  gemm_core<ACT, MIRROR>(A0, K0, cntA, A1, K1, Bp, bias, D, C, Cb, M, N,
                         blockIdx.x * 128, blockIdx.y * 128, As, Bs);
}

// Fused GRU GEMMs: z=0 -> gi = [aggR/cnt | rel_bf] @ wp_ih; z=1 -> gh = relh_bf @ wp_hh
__global__ __launch_bounds__(256, 2)
void gru_gemms(const float* __restrict__ aggR, const float* __restrict__ cntR,
               const unsigned short* __restrict__ rel_bf,
               const unsigned short* __restrict__ relh_bf,
               const unsigned short* __restrict__ wp_ih,
               const unsigned short* __restrict__ wp_hh,
               float* __restrict__ gi, float* __restrict__ gh) {
  __shared__ unsigned short As[2][8192];
  __shared__ unsigned short Bs[2][8192];
  if (blockIdx.z == 0)
    gemm_core<0, 0>(aggR, 512, cntR, rel_bf, 512, wp_ih, nullptr, nullptr,
                    gi, nullptr, N_REL, 1536, blockIdx.x * 128, blockIdx.y * 128, As, Bs);
  else
    gemm_core<0, 0>(nullptr, 0, nullptr, relh_bf, 512, wp_hh, nullptr, nullptr,
                    gh, nullptr, N_REL, 1536, blockIdx.x * 128, blockIdx.y * 128, As, Bs);
}

// ---------------------------------------------------------------------------
// pack_fw: fw (32768x512 f32) -> bf16 image (same layout as pack_nn, N=512)
// ---------------------------------------------------------------------------
__global__ __launch_bounds__(256)
void pack_fw_kernel(const float* __restrict__ f0, const float* __restrict__ f1,
                    const float* __restrict__ f2, const float* __restrict__ f3,
                    unsigned short* __restrict__ o0, unsigned short* __restrict__ o1,
                    unsigned short* __restrict__ o2, unsigned short* __restrict__ o3) {
  __shared__ float L[32][512];
  const float* fw; unsigned short* op;
  switch (blockIdx.y) {
    case 0: fw = f0; op = o0; break;
    case 1: fw = f1; op = o1; break;
    case 2: fw = f2; op = o2; break;
    default: fw = f3; op = o3; break;
  }
  int s = blockIdx.x, tid = threadIdx.x;
  #pragma unroll
  for (int i = 0; i < 16; ++i) {
    int idx = tid + 256 * i;
    int r = idx >> 7, cq = (idx & 127) << 2;
    *(float4*)&L[r][cq] = *(const float4*)&fw[(size_t)(s * 32 + r) * 512 + cq];
  }
  __syncthreads();
  #pragma unroll
  for (int ii = 0; ii < 8; ++ii) {
    int slot = tid + 256 * ii;
    int n = slot >> 2, g = slot & 3;
    u16x8 pk;
    #pragma unroll
    for (int j = 0; j < 8; ++j) pk[j] = f2bf(L[g * 8 + j][n]);
    size_t off = (size_t)s * 16384 + n * 32 + ((g ^ ((n >> 2) & 3)) << 3);
    *(u16x8*)&op[off] = pk;
  }
}

// ---------------------------------------------------------------------------
// convgen: conv1d('SAME',K=3)+relu -> A_conv bf16 [NB][c*512+h], both paths.
// ---------------------------------------------------------------------------
template <int CIN>
__global__ __launch_bounds__(256)
void convgen_kernel(const float* __restrict__ X0e, const float* __restrict__ X1e,
                    const float* __restrict__ X2e,
                    const float* __restrict__ cwE, const float* __restrict__ cbE,
                    const float* __restrict__ X0r, const float* __restrict__ X1r,
                    const float* __restrict__ X2r,
                    const float* __restrict__ cwR, const float* __restrict__ cbR,
                    unsigned short* __restrict__ Ae, unsigned short* __restrict__ Ar) {
  __shared__ float wsm[64 * CIN * 3];
  __shared__ float bsm[64];
  const int path = blockIdx.y;
  const float* X[CIN]; const float* cw; const float* cb; unsigned short* A;
  if (path == 0) {
    X[0] = X0e; X[1] = X1e; if constexpr (CIN == 3) X[2] = X2e;
    cw = cwE; cb = cbE; A = Ae;
  } else {
    X[0] = X0r; X[1] = X1r; if constexpr (CIN == 3) X[2] = X2r;
    cw = cwR; cb = cbR; A = Ar;
  }
  const int tid = threadIdx.x;
  for (int i = tid; i < 64 * CIN * 3; i += 256) wsm[i] = cw[i];
  if (tid < 64) bsm[tid] = cb[tid];
  __syncthreads();

  const int o = tid & 63;
  const int b = blockIdx.x * 4 + (tid >> 6);
  const int h = o * 8;

  float xm[CIN][8], xl[CIN], xr[CIN];
  #pragma unroll
  for (int ci = 0; ci < CIN; ++ci) {
    const float* row = X[ci] + (size_t)b * HD + h;
    float4 a4 = *(const float4*)row;
    float4 b4 = *(const float4*)(row + 4);
    xm[ci][0] = a4.x; xm[ci][1] = a4.y; xm[ci][2] = a4.z; xm[ci][3] = a4.w;
    xm[ci][4] = b4.x; xm[ci][5] = b4.y; xm[ci][6] = b4.z; xm[ci][7] = b4.w;
    xl[ci] = (h > 0) ? row[-1] : 0.f;
    xr[ci] = (h + 8 < HD) ? row[8] : 0.f;
  }
  unsigned short* dst = A + (size_t)b * 32768 + h;
  for (int c = 0; c < 64; ++c) {
    float v[8];
    float cbv = bsm[c];
    #pragma unroll
    for (int e = 0; e < 8; ++e) v[e] = cbv;
    #pragma unroll
    for (int ci = 0; ci < CIN; ++ci) {
      float w0 = wsm[(c * CIN + ci) * 3 + 0];
      float w1 = wsm[(c * CIN + ci) * 3 + 1];
      float w2 = wsm[(c * CIN + ci) * 3 + 2];
      #pragma unroll
      for (int e = 0; e < 8; ++e) {
        float lft = e ? xm[ci][e - 1] : xl[ci];
        float rgt = (e < 7) ? xm[ci][e + 1] : xr[ci];
        v[e] = fmaf(lft, w0, fmaf(xm[ci][e], w1, fmaf(rgt, w2, v[e])));
      }
    }
    u16x8 pk;
    #pragma unroll
    for (int e = 0; e < 8; ++e) pk[e] = f2bf(fmaxf(v[e], 0.f));
    *(u16x8*)&dst[c * 512] = pk;
  }
}

// ---------------------------------------------------------------------------
// gemm_fc: part[path][ks] = A_conv(4096 x 32768 bf16) @ fw-image, KSPLIT=4.
// ---------------------------------------------------------------------------
__global__ __launch_bounds__(256, 2)
void gemm_fc(const unsigned short* __restrict__ Abuf,
             const unsigned short* __restrict__ fwpE,
             const unsigned short* __restrict__ fwpR,
             float* __restrict__ partBase) {
  __shared__ unsigned short As[2][128 * 64];
  __shared__ unsigned short Bs[2][2 * 128 * 32];
  const int tid = threadIdx.x;
  const int lane = tid & 63;
  const int wv = tid >> 6;
  const int wm = wv >> 1, wn = wv & 1;
  const int lr = lane & 15, lg = lane >> 4;
  const int m0 = blockIdx.x * 128;
  const int n0 = blockIdx.y * 128;
  const int path = blockIdx.z >> 2;
  const int ks = blockIdx.z & 3;

  const unsigned short* A = Abuf + (size_t)path * ((size_t)NB * 32768);
  const unsigned short* fwp = (path == 0) ? fwpE : fwpR;
  float* part = partBase + (size_t)(path * 4 + ks) * ((size_t)NB * HD);

  const int arow = tid >> 1;
  const int achunk = (tid & 1) * 4;
  const unsigned short* aRow = A + (size_t)(m0 + arow) * 32768 + ks * 8192 + achunk * 8;
  const unsigned short* bBase = fwp + (size_t)(ks * 256) * 16384 + (size_t)n0 * 32;

  f32x4 acc[4][4];
  #pragma unroll
  for (int i = 0; i < 4; ++i)
    #pragma unroll
    for (int j = 0; j < 4; ++j) acc[i][j] = (f32x4){0.f, 0.f, 0.f, 0.f};

  auto gload = [&](int it, u16x8* ar, u16x8* br) {
    const unsigned short* ap = aRow + it * 64;
    #pragma unroll
    for (int q = 0; q < 4; ++q) ar[q] = *(const u16x8*)&ap[q * 8];
    const unsigned short* bp = bBase + (size_t)it * 2 * 16384;
    br[0] = *(const u16x8*)&bp[tid * 8];
    br[1] = *(const u16x8*)&bp[2048 + tid * 8];
    br[2] = *(const u16x8*)&bp[16384 + tid * 8];
    br[3] = *(const u16x8*)&bp[16384 + 2048 + tid * 8];
  };
  auto swrite = [&](int nb, const u16x8* ar, const u16x8* br) {
    #pragma unroll
    for (int q = 0; q < 4; ++q) {
      int chunk = achunk + q;
      *(u16x8*)&As[nb][arow * 64 + ((chunk ^ (arow & 7)) << 3)] = ar[q];
    }
    *(u16x8*)&Bs[nb][tid * 8] = br[0];
    *(u16x8*)&Bs[nb][2048 + tid * 8] = br[1];
    *(u16x8*)&Bs[nb][4096 + tid * 8] = br[2];
    *(u16x8*)&Bs[nb][4096 + 2048 + tid * 8] = br[3];
  };

  {
    u16x8 ar[4], br[4];
    gload(0, ar, br);
    swrite(0, ar, br);
  }
  __syncthreads();

  int cur = 0;
  for (int it = 0; it < 128; ++it) {
    u16x8 ar[4], br[4];
    if (it < 127) gload(it + 1, ar, br);
    bf16x8 af[2][4], bfr[2][4];
    #pragma unroll
    for (int u = 0; u < 2; ++u)
      #pragma unroll
      for (int i = 0; i < 4; ++i) {
        int r = wm * 64 + i * 16 + lr;
        af[u][i] = *(const bf16x8*)&As[cur][r * 64 + (((u * 4 + lg) ^ (r & 7)) << 3)];
        int nl = wn * 64 + i * 16 + lr;
        bfr[u][i] = *(const bf16x8*)&Bs[cur][u * 4096 + nl * 32 + ((lg ^ ((nl >> 2) & 3)) << 3)];
      }
    #pragma unroll
    for (int u = 0; u < 2; ++u)
      #pragma unroll
      for (int i = 0; i < 4; ++i)
        #pragma unroll
        for (int j = 0; j < 4; ++j)
          acc[i][j] = __builtin_amdgcn_mfma_f32_16x16x32_bf16(af[u][i], bfr[u][j], acc[i][j], 0, 0, 0);
    if (it < 127) swrite(cur ^ 1, ar, br);
    __syncthreads();
    cur ^= 1;
  }

  #pragma unroll
  for (int i = 0; i < 4; ++i) {
    int m = m0 + wm * 64 + i * 16 + lg * 4;
    #pragma unroll
    for (int j = 0; j < 4; ++j) {
      int n = n0 + wn * 64 + j * 16 + lr;
      #pragma unroll
      for (int q = 0; q < 4; ++q)
        part[(size_t)(m + q) * HD + n] = acc[i][j][q];
    }
  }
}

// ---------------------------------------------------------------------------
// reduce 4 split-K partials + bias + relu -> f32 out AND bf16 out
// ---------------------------------------------------------------------------
__global__ void reduce4_kernel(const float* __restrict__ pE, const float* __restrict__ pR,
                               const float* __restrict__ bE, const float* __restrict__ bR,
                               float* __restrict__ oE, float* __restrict__ oR,
                               unsigned short* __restrict__ obE, unsigned short* __restrict__ obR) {
  int p = blockIdx.y;
  const float* part = p ? pR : pE;
  const float* bias = p ? bR : bE;
  float* o = p ? oR : oE;
  unsigned short* ob = p ? obR : obE;
  int i = blockIdx.x * 256 + threadIdx.x;
  int col = (i << 2) & 511;
  float4 s = *(const float4*)&part[(size_t)i * 4];
  #pragma unroll
  for (int ks = 1; ks < 4; ++ks) {
    float4 t = *(const float4*)&part[(size_t)ks * (NB * HD) + i * 4];
    s.x += t.x; s.y += t.y; s.z += t.z; s.w += t.w;
  }
  float4 b4 = *(const float4*)&bias[col];
  s.x = fmaxf(s.x + b4.x, 0.f); s.y = fmaxf(s.y + b4.y, 0.f);
  s.z = fmaxf(s.z + b4.z, 0.f); s.w = fmaxf(s.w + b4.w, 0.f);
  *(float4*)&o[(size_t)i * 4] = s;
  u16x4 pk = {f2bf(s.x), f2bf(s.y), f2bf(s.z), f2bf(s.w)};
  *(u16x4*)&ob[(size_t)i * 4] = pk;
}

// ---------------------------------------------------------------------------
// bf16 NT GEMM: C(MxN, f32) = A(MxK) @ B(NxK)^T, both bf16 row-major.
// ---------------------------------------------------------------------------
__global__ __launch_bounds__(256, 3)
void gemm_nt_bf16(const unsigned short* __restrict__ A, const unsigned short* __restrict__ B,
                  float* __restrict__ C, int M, int N, int K) {
  __shared__ unsigned short As[128 * 64];
  __shared__ unsigned short Bs[128 * 64];
  const int tid = threadIdx.x;
  const int lane = tid & 63;
  const int w = tid >> 6;
  const int wm = w >> 1, wn = w & 1;
  const int m0 = blockIdx.x * 128, n0 = blockIdx.y * 128;
  const int lr = lane & 15, lg = lane >> 4;

  f32x4 acc[4][4];
  #pragma unroll
  for (int i = 0; i < 4; ++i)
    #pragma unroll
    for (int j = 0; j < 4; ++j) acc[i][j] = (f32x4){0.f, 0.f, 0.f, 0.f};

  for (int k0 = 0; k0 < K; k0 += 64) {
    __syncthreads();
    {
      int row = tid >> 1, half = tid & 1;
      const unsigned short* asrc = A + (size_t)(m0 + row) * K + k0 + half * 32;
      #pragma unroll
      for (int q = 0; q < 4; ++q) {
        int chunk = half * 4 + q;
        *(u16x8*)&As[row * 64 + (chunk ^ (row & 7)) * 8] = *(const u16x8*)&asrc[q * 8];
      }
      int nrow = n0 + row;
      const unsigned short* bsrc = B + (size_t)nrow * K + k0 + half * 32;
      u16x8 z = {0, 0, 0, 0, 0, 0, 0, 0};
      #pragma unroll
      for (int q = 0; q < 4; ++q) {
        int chunk = half * 4 + q;
        u16x8 v = (nrow < N) ? *(const u16x8*)&bsrc[q * 8] : z;
        *(u16x8*)&Bs[row * 64 + (chunk ^ (row & 7)) * 8] = v;
      }
    }
    __syncthreads();
    #pragma unroll
    for (int u = 0; u < 2; ++u) {
      bf16x8 a[4], b[4];
      #pragma unroll
      for (int i = 0; i < 4; ++i) {
        int r = wm * 64 + i * 16 + lr;
        a[i] = *(const bf16x8*)&As[r * 64 + (((u * 4 + lg) ^ (r & 7))) * 8];
        int n = wn * 64 + i * 16 + lr;
        b[i] = *(const bf16x8*)&Bs[n * 64 + (((u * 4 + lg) ^ (n & 7))) * 8];
      }
      #pragma unroll
      for (int i = 0; i < 4; ++i)
        #pragma unroll
        for (int j = 0; j < 4; ++j)
          acc[i][j] = __builtin_amdgcn_mfma_f32_16x16x32_bf16(a[i], b[j], acc[i][j], 0, 0, 0);
    }
  }

  #pragma unroll
  for (int i = 0; i < 4; ++i) {
    int m = m0 + wm * 64 + i * 16 + lg * 4;
    #pragma unroll
    for (int j = 0; j < 4; ++j) {
      int n = n0 + wn * 64 + j * 16 + lr;
      if (n < N) {
        #pragma unroll
        for (int q = 0; q < 4; ++q)
          C[(size_t)(m + q) * N + n] = acc[i][j][q];
      }
    }
  }
}

// ---------------------------------------------------------------------------
extern "C" void kernel_launch(void* const* d_in, const int* in_sizes, int n_in,
                              void* d_out, int out_size, void* d_ws, size_t ws_size,
                              hipStream_t stream) {
  const float* ent_embeds = (const float*)d_in[0];
  const float* rel_embeds = (const float*)d_in[1];
  const float* W_msg  = (const float*)d_in[2];
  const float* W_self = (const float*)d_in[3];
  const float* gru_Wih = (const float*)d_in[4];
  const float* gru_Whh = (const float*)d_in[5];
  const float* gru_bih = (const float*)d_in[6];
  const float* gru_bhh = (const float*)d_in[7];
  const float* gate_W = (const float*)d_in[8];
  const float* gate_b = (const float*)d_in[9];
  const float* e_conv1 = (const float*)d_in[10]; const float* e_cb1 = (const float*)d_in[11];
  const float* e_fc1   = (const float*)d_in[12]; const float* e_fb1 = (const float*)d_in[13];
  const float* e_conv2 = (const float*)d_in[14]; const float* e_cb2 = (const float*)d_in[15];
  const float* e_fc2   = (const float*)d_in[16]; const float* e_fb2 = (const float*)d_in[17];
  const float* r_conv1 = (const float*)d_in[18]; const float* r_cb1 = (const float*)d_in[19];
  const float* r_fc1   = (const float*)d_in[20]; const float* r_fb1 = (const float*)d_in[21];
  const float* r_conv2 = (const float*)d_in[22]; const float* r_cb2 = (const float*)d_in[23];
  const float* r_fc2   = (const float*)d_in[24]; const float* r_fb2 = (const float*)d_in[25];
  const int* src  = (const int*)d_in[26];
  const int* dst  = (const int*)d_in[27];
  const int* erel = (const int*)d_in[28];
  const int* subj = (const int*)d_in[29];
  const int* rel  = (const int*)d_in[30];
  const int* obj  = (const int*)d_in[31];
  float* out = (float*)d_out;

  // -------- workspace layout --------
  float* w = (float*)d_ws;
  float* ent   = w; w += (size_t)N_ENT * HD;
  float* relh  = w; w += (size_t)N_REL * HD;
  float* aggR  = w; w += (size_t)N_REL * HD;
  float* cntR  = w; w += N_REL;
  float* gi    = w; w += (size_t)N_REL * 1536;
  float* gh    = w; w += (size_t)N_REL * 1536;
  float* aggE  = w; w += (size_t)N_ENT * HD;     // } aggE..h1b reused post-loop as
  float* cntE  = w; w += N_ENT;                  // } packed-fw storage
  float* tmp   = w; w += (size_t)N_ENT * HD;
  float* h0b   = w; w += (size_t)N_ENT * HD;
  float* h1b   = w; w += (size_t)N_ENT * HD;
  float* se    = w; w += (size_t)NB * HD;
  float* re_   = w; w += (size_t)NB * HD;
  float* oe    = w; w += (size_t)NB * HD;
  float* o1    = w; w += (size_t)NB * HD;
  float* q1    = w; w += (size_t)NB * HD;
  float* o2    = w; w += (size_t)NB * HD;
  float* q2    = w; w += (size_t)NB * HD;
  unsigned short* ent_bf = (unsigned short*)w; w += (size_t)N_ENT * HD / 2;
  unsigned short* relh_bf = (unsigned short*)w; w += (size_t)N_REL * HD / 2;
  unsigned short* rel_bf = (unsigned short*)w; w += (size_t)N_REL * HD / 2;
  unsigned short* h0b_bf = (unsigned short*)w; w += (size_t)N_ENT * HD / 2;
  unsigned short* h1b_bf = (unsigned short*)w; w += (size_t)N_ENT * HD / 2;
  unsigned short* o1b = (unsigned short*)w; w += (size_t)NB * HD / 2;
  unsigned short* q1b = (unsigned short*)w; w += (size_t)NB * HD / 2;
  unsigned short* o2b = (unsigned short*)w; w += (size_t)NB * HD / 2;
  unsigned short* q2b = (unsigned short*)w; w += (size_t)NB * HD / 2;
  // recurrence weight packs (bf16), live across the whole call
  unsigned short* wp_ih = (unsigned short*)w;    // 1024x1536
  unsigned short* wp_hh = wp_ih + (size_t)1024 * 1536;
  unsigned short* wp_l0 = wp_hh + (size_t)512 * 1536;
  unsigned short* wp_l1 = wp_l0 + (size_t)1024 * 512;
  unsigned short* wp_g  = wp_l1 + (size_t)1024 * 512;
  // fw packs alias the recurrence temporaries (used only post-loop)
  unsigned short* fwp0 = (unsigned short*)aggE;
  unsigned short* fwp1 = fwp0 + (size_t)16777216;
  unsigned short* fwp2 = fwp1 + (size_t)16777216;
  unsigned short* fwp3 = fwp2 + (size_t)16777216;
  (void)tmp; (void)h0b;
  // decoder scratch in d_out (written+consumed before logits):
  unsigned short* Abuf = (unsigned short*)out;          // 2 x NB x 32768 u16
  float* pE = out + (size_t)134217728 / 2 / 2 * 2;      // = out + 67108864? no:
  // A_conv occupies 2*NB*32768 u16 = 268435456 B = 67108864 f32 slots... keep explicit:
  pE = out + (size_t)2 * NB * 32768 / 2;                // u16 count /2 = f32 offset
  float* pR = pE + (size_t)4 * NB * HD;

  const dim3 g_gru(2, 12, 2);  // 256 x 1536, z = {gi, gh}
  const dim3 g_ent(157, 4);    // 20000 x 512

  // -------- weight packing (once) --------
  {
    int t;
    t = (1024 * 1536) / 8; pack_nn_kernel<<<(t + 255) / 256, 256, 0, stream>>>(gru_Wih, wp_ih, 1024, 1536);
    t = (512 * 1536) / 8;  pack_nn_kernel<<<(t + 255) / 256, 256, 0, stream>>>(gru_Whh, wp_hh, 512, 1536);
    t = (512 * 512) / 8;
    pack_nn_kernel<<<(t + 255) / 256, 256, 0, stream>>>(W_msg, wp_l0, 512, 512);
    pack_nn_kernel<<<(t + 255) / 256, 256, 0, stream>>>(W_self, wp_l0 + (size_t)512 * 512, 512, 512);
    pack_nn_kernel<<<(t + 255) / 256, 256, 0, stream>>>(W_msg + (size_t)512 * 512, wp_l1, 512, 512);
    pack_nn_kernel<<<(t + 255) / 256, 256, 0, stream>>>(W_self + (size_t)512 * 512, wp_l1 + (size_t)512 * 512, 512, 512);
    pack_nn_kernel<<<(t + 255) / 256, 256, 0, stream>>>(gate_W, wp_g, 512, 512);
  }

  // -------- init --------
  rownorm_kernel<<<N_ENT / 4, 256, 0, stream>>>(ent_embeds, ent, ent_bf, N_ENT);
  hipMemcpyAsync(relh, rel_embeds, (size_t)N_REL * HD * 4, hipMemcpyDeviceToDevice, stream);
  f2b_kernel<<<(N_REL * HD / 8) / 256, 256, 0, stream>>>(rel_embeds, rel_bf, N_REL * HD);
  f2b_kernel<<<(N_REL * HD / 8) / 256, 256, 0, stream>>>(rel_embeds, relh_bf, N_REL * HD);

  // -------- timestep loop --------
  for (int t = 0; t < NT; ++t) {
    const int* st = src + t * NE;
    const int* dt = dst + t * NE;
    const int* rt = erel + t * NE;

    hipMemsetAsync(aggR, 0, ((size_t)N_REL * HD + N_REL) * 4, stream);
    agg_rel_kernel<<<NE / 4, 256, 0, stream>>>(ent, st, rt, aggR, cntR);
    gru_gemms<<<g_gru, 256, 0, stream>>>(aggR, cntR, rel_bf, relh_bf, wp_ih, wp_hh, gi, gh);
    gru_kernel<<<(N_REL * HD) / 256, 256, 0, stream>>>(gi, gh, gru_bih, gru_bhh, relh, relh_bf);

    // entity evolution: h = relu([mean-agg | h] @ [Wmsg;Wself]) per layer
    hipMemsetAsync(aggE, 0, ((size_t)N_ENT * HD + N_ENT) * 4, stream);
    agg_ent_kernel<<<NE / 4, 256, 0, stream>>>(ent, relh, st, dt, rt, aggE, cntE);
    gemm_nn2<1, 1><<<g_ent, 256, 0, stream>>>(aggE, 512, cntE, ent_bf, 512, wp_l0,
                                              nullptr, nullptr, h0b, h0b_bf, N_ENT, 512);
    hipMemsetAsync(aggE, 0, ((size_t)N_ENT * HD + N_ENT) * 4, stream);
    agg_ent_kernel<<<NE / 4, 256, 0, stream>>>(h0b, relh, st, dt, rt, aggE, cntE);
    gemm_nn2<1, 0><<<g_ent, 256, 0, stream>>>(aggE, 512, cntE, h0b_bf, 512, wp_l1,
                                              nullptr, nullptr, h1b, nullptr, N_ENT, 512);
    rownorm_kernel<<<N_ENT / 4, 256, 0, stream>>>(h1b, h1b, h1b_bf, N_ENT);
    gemm_nn2<3, 1><<<g_ent, 256, 0, stream>>>(nullptr, 0, nullptr, h1b_bf, 512, wp_g,
                                              gate_b, h1b, ent, ent_bf, N_ENT, 512);
  }

  // -------- decoder prep --------
  pack_fw_kernel<<<dim3(1024, 4), 256, 0, stream>>>(e_fc1, r_fc1, e_fc2, r_fc2,
                                                    fwp0, fwp1, fwp2, fwp3);
  gather_kernel<<<(NB * HD / 4) / 256, 256, 0, stream>>>(ent, subj, se, NB);
  gather_kernel<<<(NB * HD / 4) / 256, 256, 0, stream>>>(relh, rel, re_, NB);
  gather_kernel<<<(NB * HD / 4) / 256, 256, 0, stream>>>(ent, obj, oe, NB);

  unsigned short* A_E = Abuf;
  unsigned short* A_R = Abuf + (size_t)NB * 32768;

  // -------- decoder stage 1 --------
  convgen_kernel<2><<<dim3(NB / 4, 2), 256, 0, stream>>>(
      se, re_, nullptr, e_conv1, e_cb1,
      se, oe, nullptr, r_conv1, r_cb1, A_E, A_R);
  gemm_fc<<<dim3(32, 4, 8), 256, 0, stream>>>(Abuf, fwp0, fwp1, pE);
  reduce4_kernel<<<dim3(NB * HD / 4 / 256, 2), 256, 0, stream>>>(
      pE, pR, e_fb1, r_fb1, o1, q1, o1b, q1b);

  // -------- decoder stage 2 --------
  convgen_kernel<3><<<dim3(NB / 4, 2), 256, 0, stream>>>(
      o1, se, re_, e_conv2, e_cb2,
      q1, se, oe, r_conv2, r_cb2, A_E, A_R);
  gemm_fc<<<dim3(32, 4, 8), 256, 0, stream>>>(Abuf, fwp2, fwp3, pE);
  reduce4_kernel<<<dim3(NB * HD / 4 / 256, 2), 256, 0, stream>>>(
      pE, pR, e_fb2, r_fb2, o2, q2, o2b, q2b);

  // -------- logits (bf16 MFMA) --------
  size_t off0 = 0;
  size_t off1 = (size_t)NB * N_ENT;
  size_t off2 = off1 + (size_t)NB * N_REL;
  size_t off3 = off2 + (size_t)NB * N_ENT;
  gemm_nt_bf16<<<dim3(32, 157), 256, 0, stream>>>(o1b, ent_bf, out + off0, NB, N_ENT, HD);
  gemm_nt_bf16<<<dim3(32, 2), 256, 0, stream>>>(q1b, relh_bf, out + off1, NB, N_REL, HD);
  gemm_nt_bf16<<<dim3(32, 157), 256, 0, stream>>>(o2b, ent_bf, out + off2, NB, N_ENT, HD);
  gemm_nt_bf16<<<dim3(32, 2), 256, 0, stream>>>(q2b, relh_bf, out + off3, NB, N_REL, HD);
}